// Round 1
// baseline (2707.350 us; speedup 1.0000x reference)
//
#include <hip/hip_runtime.h>
#include <math.h>

#define S_LEN 2048
#define HID 2048
#define NH 16
#define NKH 8
#define HD 128
#define QKV_N 4096          // 2048 q + 1024 k + 1024 v rows
#define SCALE 0.08838834764831845f
#define EPS 1e-6f

// ---------------------------------------------------------------------------
// GEMM: C[M x N] = A[M x K] * B[N x K]^T  (both row-major, "bt" pattern)
// B rows come from up to three source matrices split at split1/split2.
// Tile 64x64, K-tile 32, 256 threads, 4x4 micro-tile per thread.
// ---------------------------------------------------------------------------
__global__ __launch_bounds__(256) void gemm_bt(
    const float* __restrict__ A,
    const float* __restrict__ B0, const float* __restrict__ B1,
    const float* __restrict__ B2,
    float* __restrict__ C,
    int M, int N, int K, int split1, int split2)
{
    __shared__ float As[32][65];   // [k][m], pad -> conflict-free
    __shared__ float Bs[32][65];   // [k][n]

    const int tid = threadIdx.x;
    const int n0 = blockIdx.x * 64;
    const int m0 = blockIdx.y * 64;
    const int ty = tid >> 4;       // 0..15 -> m rows ty*4..+3
    const int tx = tid & 15;       // 0..15 -> n cols tx*4..+3

    float acc[4][4] = {};

    for (int k0 = 0; k0 < K; k0 += 32) {
        // stage A tile: 64 rows x 32 k
        #pragma unroll
        for (int it = 0; it < 8; ++it) {
            int idx = it * 256 + tid;
            int m = idx >> 5, k = idx & 31;
            As[k][m] = A[(size_t)(m0 + m) * K + k0 + k];
        }
        // stage B tile: 64 rows x 32 k with 3-way row split
        #pragma unroll
        for (int it = 0; it < 8; ++it) {
            int idx = it * 256 + tid;
            int n = idx >> 5, k = idx & 31;
            int ng = n0 + n;
            const float* brow;
            if (ng < split1)      brow = B0 + (size_t)ng * K;
            else if (ng < split2) brow = B1 + (size_t)(ng - split1) * K;
            else                  brow = B2 + (size_t)(ng - split2) * K;
            Bs[k][n] = brow[k0 + k];
        }
        __syncthreads();

        #pragma unroll 8
        for (int k = 0; k < 32; ++k) {
            float a[4], b[4];
            #pragma unroll
            for (int i = 0; i < 4; ++i) a[i] = As[k][ty * 4 + i];
            #pragma unroll
            for (int j = 0; j < 4; ++j) b[j] = Bs[k][tx * 4 + j];
            #pragma unroll
            for (int i = 0; i < 4; ++i)
                #pragma unroll
                for (int j = 0; j < 4; ++j)
                    acc[i][j] += a[i] * b[j];
        }
        __syncthreads();
    }

    #pragma unroll
    for (int i = 0; i < 4; ++i) {
        float4 v = make_float4(acc[i][0], acc[i][1], acc[i][2], acc[i][3]);
        *(float4*)&C[(size_t)(m0 + ty * 4 + i) * N + n0 + tx * 4] = v;
    }
}

// ---------------------------------------------------------------------------
// RMSNorm + RoPE, in place on the qkv buffer. grid = (S, NH+NKH), block = 128.
// blockIdx.y < NH -> q head; else k head (also emits k_new/v_new at s = S-1).
// ---------------------------------------------------------------------------
__global__ __launch_bounds__(128) void norm_rope(
    float* __restrict__ qkv,
    const float* __restrict__ cosb, const float* __restrict__ sinb,
    const float* __restrict__ qw, const float* __restrict__ kw,
    float* __restrict__ knew, float* __restrict__ vnew)
{
    const int s = blockIdx.x;
    const int h = blockIdx.y;
    const int d = threadIdx.x;

    float* row;
    const float* w;
    int kh = -1;
    if (h < NH) {
        row = qkv + (size_t)s * QKV_N + h * HD;
        w = qw;
    } else {
        kh = h - NH;
        row = qkv + (size_t)s * QKV_N + HID + kh * HD;
        w = kw;
    }

    float x = row[d];
    float ss = x * x;
    #pragma unroll
    for (int off = 32; off >= 1; off >>= 1) ss += __shfl_xor(ss, off, 64);

    __shared__ float sred[2];
    __shared__ float xn[128];
    int lane = d & 63, wid = d >> 6;
    if (lane == 0) sred[wid] = ss;
    __syncthreads();
    float total = sred[0] + sred[1];
    float r = rsqrtf(total * (1.0f / 128.0f) + EPS);
    xn[d] = x * r * w[d];
    __syncthreads();

    float res;
    if (d < 64) {
        float c = cosb[s * 64 + d], sn = sinb[s * 64 + d];
        res = xn[d] * c - xn[d + 64] * sn;
    } else {
        int d2 = d - 64;
        float c = cosb[s * 64 + d2], sn = sinb[s * 64 + d2];
        res = xn[d2] * sn + xn[d] * c;
    }
    row[d] = res;

    if (kh >= 0 && s == S_LEN - 1) {
        knew[kh * HD + d] = res;
        vnew[kh * HD + d] = qkv[(size_t)s * QKV_N + HID + NKH * HD + kh * HD + d];
    }
}

// ---------------------------------------------------------------------------
// Causal GQA flash attention, fp32. grid = (S/32, NH), block = 256.
// Q tile 32x128 (pre-scaled), K/V tiles 32x128 staged per iteration.
// Thread t: qi = t>>3 (score row & accум row), PV d-slice = (t&7) + 8*i.
// ---------------------------------------------------------------------------
__global__ __launch_bounds__(256) void attn(
    const float* __restrict__ qkv, float* __restrict__ out)
{
    const int qb = blockIdx.x;
    const int h = blockIdx.y;
    const int kvh = h >> 1;    // GROUPS = 2
    const int tid = threadIdx.x;

    __shared__ float Qs[32][129];
    __shared__ float Ks[32][129];
    __shared__ float Vs[32][129];
    __shared__ float Ps[32][33];
    __shared__ float mrow[32], lrow[32], arow[32];

    // load + pre-scale Q tile
    #pragma unroll
    for (int it = 0; it < 16; ++it) {
        int idx = it * 256 + tid;
        int r = idx >> 7, d = idx & 127;
        Qs[r][d] = qkv[(size_t)(qb * 32 + r) * QKV_N + h * HD + d] * SCALE;
    }
    if (tid < 32) { mrow[tid] = -INFINITY; lrow[tid] = 0.0f; }

    float acc[16];
    #pragma unroll
    for (int i = 0; i < 16; ++i) acc[i] = 0.0f;

    const int qi = tid >> 3;        // 0..31
    const int dj = tid & 7;         // PV d-slice base (stride-8 mapping)
    const int jsc = (tid & 7) * 4;  // score columns jsc..jsc+3
    const int qg = qb * 32 + qi;
    __syncthreads();

    for (int kb = 0; kb <= qb; ++kb) {
        #pragma unroll
        for (int it = 0; it < 16; ++it) {
            int idx = it * 256 + tid;
            int r = idx >> 7, d = idx & 127;
            size_t base = (size_t)(kb * 32 + r) * QKV_N;
            Ks[r][d] = qkv[base + HID + kvh * HD + d];
            Vs[r][d] = qkv[base + HID + NKH * HD + kvh * HD + d];
        }
        __syncthreads();

        // scores
        float sc[4] = {0, 0, 0, 0};
        for (int d = 0; d < 128; ++d) {
            float qv = Qs[qi][d];
            #pragma unroll
            for (int j = 0; j < 4; ++j) sc[j] += qv * Ks[jsc + j][d];
        }
        #pragma unroll
        for (int j = 0; j < 4; ++j) {
            int kg = kb * 32 + jsc + j;
            Ps[qi][jsc + j] = (kg <= qg) ? sc[j] : -1e9f;
        }
        __syncthreads();

        // online softmax, one thread per q-row
        if (tid < 32) {
            float m_old = mrow[tid];
            float tm = m_old;
            #pragma unroll 8
            for (int j = 0; j < 32; ++j) tm = fmaxf(tm, Ps[tid][j]);
            float alpha = expf(m_old - tm);
            float sum = 0.0f;
            #pragma unroll 8
            for (int j = 0; j < 32; ++j) {
                float p = expf(Ps[tid][j] - tm);
                Ps[tid][j] = p;
                sum += p;
            }
            lrow[tid] = lrow[tid] * alpha + sum;
            mrow[tid] = tm;
            arow[tid] = alpha;
        }
        __syncthreads();

        float al = arow[qi];
        #pragma unroll
        for (int i = 0; i < 16; ++i) acc[i] *= al;
        for (int j = 0; j < 32; ++j) {
            float p = Ps[qi][j];
            #pragma unroll
            for (int i = 0; i < 16; ++i) acc[i] += p * Vs[j][dj + 8 * i];
        }
        __syncthreads();
    }

    float rl = 1.0f / lrow[qi];
    #pragma unroll
    for (int i = 0; i < 16; ++i)
        out[(size_t)qg * HID + h * HD + dj + 8 * i] = acc[i] * rl;
}

// ---------------------------------------------------------------------------
extern "C" void kernel_launch(void* const* d_in, const int* in_sizes, int n_in,
                              void* d_out, int out_size, void* d_ws, size_t ws_size,
                              hipStream_t stream) {
    const float* hidden = (const float*)d_in[0];
    const float* fcos   = (const float*)d_in[1];
    const float* fsin   = (const float*)d_in[2];
    // d_in[3] atten_mask: causal, applied analytically
    const float* Wq = (const float*)d_in[4];
    const float* Wk = (const float*)d_in[5];
    const float* Wv = (const float*)d_in[6];
    const float* Wo = (const float*)d_in[7];
    const float* qw = (const float*)d_in[8];
    const float* kw = (const float*)d_in[9];
    float* out = (float*)d_out;

    float* qkv = (float*)d_ws;                       // S x 4096 (q|k|v)
    float* attn_out = qkv + (size_t)S_LEN * QKV_N;   // S x 2048

    float* knew = out + (size_t)S_LEN * HID;
    float* vnew = knew + NKH * HD;

    // 1) fused QKV projection: C = hidden * [Wq;Wk;Wv]^T
    gemm_bt<<<dim3(QKV_N / 64, S_LEN / 64), 256, 0, stream>>>(
        hidden, Wq, Wk, Wv, qkv, S_LEN, QKV_N, HID, HID, HID + NKH * HD);

    // 2) RMSNorm + RoPE on q,k (in place) + k_new/v_new extraction
    norm_rope<<<dim3(S_LEN, NH + NKH), 128, 0, stream>>>(
        qkv, fcos, fsin, qw, kw, knew, vnew);

    // 3) causal GQA attention
    attn<<<dim3(S_LEN / 32, NH), 256, 0, stream>>>(qkv, attn_out);

    // 4) output projection: y = attn_out * Wo^T
    gemm_bt<<<dim3(HID / 64, S_LEN / 64), 256, 0, stream>>>(
        attn_out, Wo, Wo, Wo, out, S_LEN, HID, HID, HID, HID);
}

// Round 2
// 473.857 us; speedup vs baseline: 5.7134x; 5.7134x over previous
//
#include <hip/hip_runtime.h>
#include <hip/hip_bf16.h>
#include <math.h>

#define S_LEN 2048
#define HID 2048
#define NH 16
#define NKH 8
#define HD 128
#define QKV_N 4096
#define SCALE 0.08838834764831845f
#define EPS 1e-6f
#define LOG2E 1.4426950408889634f

typedef __hip_bfloat16 bf16;
typedef __bf16 bf16x8 __attribute__((ext_vector_type(8)));
typedef float f32x4 __attribute__((ext_vector_type(4)));

#define MFMA(a, b, c) __builtin_amdgcn_mfma_f32_16x16x32_bf16(a, b, c, 0, 0, 0)

static __device__ __forceinline__ bf16x8 ld_frag(const bf16* p) {
    return __builtin_bit_cast(bf16x8, *(const uint4*)p);
}

// ---------------------------------------------------------------------------
// fp32 -> bf16 conversion, float4-vectorized
// ---------------------------------------------------------------------------
__global__ __launch_bounds__(256) void cvt_bf16(
    const float* __restrict__ src, bf16* __restrict__ dst, int n4)
{
    int i = blockIdx.x * 256 + threadIdx.x;
    if (i < n4) {
        float4 v = ((const float4*)src)[i];
        bf16* d = dst + 4 * (size_t)i;
        d[0] = __float2bfloat16(v.x);
        d[1] = __float2bfloat16(v.y);
        d[2] = __float2bfloat16(v.z);
        d[3] = __float2bfloat16(v.w);
    }
}

// ---------------------------------------------------------------------------
// bf16 MFMA GEMM: C[M][N] = A[M][K] * B[N][K]^T. 128x128 tile, BK=32.
// 4 waves, each owns a 64x64 quadrant as 4x4 grid of 16x16x32 MFMAs.
// LDS rows padded to 40 elements (80 B = 20 words -> 2-way max on frag reads).
// ---------------------------------------------------------------------------
template <int BF16OUT>
__global__ __launch_bounds__(256) void gemm_bt(
    const bf16* __restrict__ A, const bf16* __restrict__ B,
    void* __restrict__ Cv, int M, int N, int K)
{
    __shared__ bf16 As[128][40];
    __shared__ bf16 Bs[128][40];
    const int tid = threadIdx.x;
    const int n0 = blockIdx.x * 128, m0 = blockIdx.y * 128;
    const int w = tid >> 6, lane = tid & 63;
    const int l15 = lane & 15, quad = lane >> 4;
    const int wr = (w >> 1) * 64, wc = (w & 1) * 64;

    f32x4 acc[4][4];
    #pragma unroll
    for (int i = 0; i < 4; ++i)
        #pragma unroll
        for (int j = 0; j < 4; ++j)
            acc[i][j] = f32x4{0.f, 0.f, 0.f, 0.f};

    const int r0 = tid >> 2;            // staging row (first half)
    const int c0 = (tid & 3) * 8;       // staging k-offset

    for (int k0 = 0; k0 < K; k0 += 32) {
        uint4 a0 = *(const uint4*)(A + (size_t)(m0 + r0) * K + k0 + c0);
        uint4 a1 = *(const uint4*)(A + (size_t)(m0 + r0 + 64) * K + k0 + c0);
        uint4 b0 = *(const uint4*)(B + (size_t)(n0 + r0) * K + k0 + c0);
        uint4 b1 = *(const uint4*)(B + (size_t)(n0 + r0 + 64) * K + k0 + c0);
        __syncthreads();
        *(uint4*)&As[r0][c0] = a0;
        *(uint4*)&As[r0 + 64][c0] = a1;
        *(uint4*)&Bs[r0][c0] = b0;
        *(uint4*)&Bs[r0 + 64][c0] = b1;
        __syncthreads();

        bf16x8 av[4], bv[4];
        #pragma unroll
        for (int i = 0; i < 4; ++i) av[i] = ld_frag(&As[wr + i * 16 + l15][quad * 8]);
        #pragma unroll
        for (int j = 0; j < 4; ++j) bv[j] = ld_frag(&Bs[wc + j * 16 + l15][quad * 8]);
        #pragma unroll
        for (int i = 0; i < 4; ++i)
            #pragma unroll
            for (int j = 0; j < 4; ++j)
                acc[i][j] = MFMA(av[i], bv[j], acc[i][j]);
    }

    #pragma unroll
    for (int i = 0; i < 4; ++i)
        #pragma unroll
        for (int j = 0; j < 4; ++j)
            #pragma unroll
            for (int r = 0; r < 4; ++r) {
                int row = m0 + wr + i * 16 + quad * 4 + r;
                int col = n0 + wc + j * 16 + l15;
                if (BF16OUT)
                    ((bf16*)Cv)[(size_t)row * N + col] = __float2bfloat16(acc[i][j][r]);
                else
                    ((float*)Cv)[(size_t)row * N + col] = acc[i][j][r];
            }
}

// ---------------------------------------------------------------------------
// RMSNorm + RoPE in place on bf16 qkv. q rows pre-scaled by SCALE.
// grid (S, NH+NKH), block 128. k path also emits fp32 k_new/v_new at s=S-1.
// ---------------------------------------------------------------------------
__global__ __launch_bounds__(128) void norm_rope(
    bf16* __restrict__ qkvb,
    const float* __restrict__ cosb, const float* __restrict__ sinb,
    const float* __restrict__ qw, const float* __restrict__ kw,
    float* __restrict__ knew, float* __restrict__ vnew)
{
    const int s = blockIdx.x;
    const int h = blockIdx.y;
    const int d = threadIdx.x;

    bf16* row;
    const float* wgt;
    int kh = -1;
    if (h < NH) {
        row = qkvb + (size_t)s * QKV_N + h * HD;
        wgt = qw;
    } else {
        kh = h - NH;
        row = qkvb + (size_t)s * QKV_N + HID + kh * HD;
        wgt = kw;
    }

    float x = __bfloat162float(row[d]);
    float ss = x * x;
    #pragma unroll
    for (int off = 32; off >= 1; off >>= 1) ss += __shfl_xor(ss, off, 64);

    __shared__ float sred[2];
    __shared__ float xn[128];
    int lane = d & 63, wid = d >> 6;
    if (lane == 0) sred[wid] = ss;
    __syncthreads();
    float total = sred[0] + sred[1];
    float rr = rsqrtf(total * (1.0f / 128.0f) + EPS);
    xn[d] = x * rr * wgt[d];
    __syncthreads();

    float res;
    if (d < 64) {
        float c = cosb[s * 64 + d], sn = sinb[s * 64 + d];
        res = xn[d] * c - xn[d + 64] * sn;
    } else {
        int d2 = d - 64;
        float c = cosb[s * 64 + d2], sn = sinb[s * 64 + d2];
        res = xn[d2] * sn + xn[d] * c;
    }

    float store_val = (h < NH) ? res * SCALE : res;
    row[d] = __float2bfloat16(store_val);

    if (kh >= 0 && s == S_LEN - 1) {
        knew[kh * HD + d] = res;
        vnew[kh * HD + d] =
            __bfloat162float(qkvb[(size_t)s * QKV_N + HID + NKH * HD + kh * HD + d]);
    }
}

// ---------------------------------------------------------------------------
// v transpose: qkv_bf v-part [s][r] -> vT[r][s]  (r = kvh*128+d, 1024 rows).
// Coalesced reads (lanes along r); 16B scattered writes (absorbed by L2).
// ---------------------------------------------------------------------------
__global__ __launch_bounds__(256) void transpose_v(
    const bf16* __restrict__ qkvb, bf16* __restrict__ vT)
{
    const int r0 = blockIdx.x * 64;
    const int s0 = blockIdx.y * 32;
    const int rl = threadIdx.x & 63, sg = threadIdx.x >> 6;

    union { uint4 u; bf16 b[8]; } pk;
    #pragma unroll
    for (int j = 0; j < 8; ++j)
        pk.b[j] = qkvb[(size_t)(s0 + sg * 8 + j) * QKV_N + HID + NKH * HD + r0 + rl];
    *(uint4*)(vT + (size_t)(r0 + rl) * S_LEN + s0 + sg * 8) = pk.u;
}

// ---------------------------------------------------------------------------
// Flash attention, bf16 MFMA. grid (S/128, NH), 256 threads (4 waves).
// Wave w owns q rows qb*128 + w*32 .. +31 (2 m-groups of 16).
// K tile 64 keys: Ks[key][d], Vs = V^T tile [d][key], Ps per-wave P.
// ---------------------------------------------------------------------------
__global__ __launch_bounds__(256) void attn_mfma(
    const bf16* __restrict__ qkvb, const bf16* __restrict__ vT,
    bf16* __restrict__ outb)
{
    const int qb = blockIdx.x, h = blockIdx.y, kvh = h >> 1;
    const int tid = threadIdx.x, w = tid >> 6, lane = tid & 63;
    const int l15 = lane & 15, quad = lane >> 4;

    __shared__ bf16 Ks[64][152];    // stride 304 B = 76 words (12 mod 32)
    __shared__ bf16 Vs[128][88];    // stride 176 B = 44 words (12 mod 32)
    __shared__ bf16 Ps[4][32][88];

    const int qw0 = qb * 128 + w * 32;

    // Q fragments (A layout), direct from global, pre-scaled by SCALE upstream
    bf16x8 qf[2][4];
    #pragma unroll
    for (int mg = 0; mg < 2; ++mg)
        #pragma unroll
        for (int dk = 0; dk < 4; ++dk)
            qf[mg][dk] = ld_frag(qkvb + (size_t)(qw0 + mg * 16 + l15) * QKV_N +
                                 h * HD + dk * 32 + quad * 8);

    f32x4 o[2][8];
    #pragma unroll
    for (int mg = 0; mg < 2; ++mg)
        #pragma unroll
        for (int dg = 0; dg < 8; ++dg)
            o[mg][dg] = f32x4{0.f, 0.f, 0.f, 0.f};

    float m_st[2][4], l_st[2][4];
    #pragma unroll
    for (int mg = 0; mg < 2; ++mg)
        #pragma unroll
        for (int r = 0; r < 4; ++r) { m_st[mg][r] = -1e30f; l_st[mg][r] = 0.f; }

    const int tmax = 2 * qb + 1;
    for (int t = 0; t <= tmax; ++t) {
        const int kt0 = t * 64;

        // cooperative staging: K tile + V^T tile
        uint4 kv[4], vv[4];
        #pragma unroll
        for (int i = 0; i < 4; ++i) {
            int idx = i * 256 + tid;
            kv[i] = *(const uint4*)(qkvb + (size_t)(kt0 + (idx >> 4)) * QKV_N +
                                    HID + kvh * HD + (idx & 15) * 8);
            vv[i] = *(const uint4*)(vT + (size_t)(kvh * HD + (idx >> 3)) * S_LEN +
                                    kt0 + (idx & 7) * 8);
        }
        __syncthreads();
        #pragma unroll
        for (int i = 0; i < 4; ++i) {
            int idx = i * 256 + tid;
            *(uint4*)&Ks[idx >> 4][(idx & 15) * 8] = kv[i];
            *(uint4*)&Vs[idx >> 3][(idx & 7) * 8] = vv[i];
        }
        __syncthreads();

        if (kt0 <= qw0 + 31) {   // wave has unmasked work in this tile
            // ---- scores: S = Q K^T ----
            f32x4 sc[2][4];
            #pragma unroll
            for (int mg = 0; mg < 2; ++mg)
                #pragma unroll
                for (int ng = 0; ng < 4; ++ng)
                    sc[mg][ng] = f32x4{0.f, 0.f, 0.f, 0.f};
            #pragma unroll
            for (int ng = 0; ng < 4; ++ng)
                #pragma unroll
                for (int dk = 0; dk < 4; ++dk) {
                    bf16x8 bk = ld_frag(&Ks[ng * 16 + l15][dk * 32 + quad * 8]);
                    sc[0][ng] = MFMA(qf[0][dk], bk, sc[0][ng]);
                    sc[1][ng] = MFMA(qf[1][dk], bk, sc[1][ng]);
                }

            // ---- causal mask (only near diagonal) ----
            if (kt0 + 63 > qw0) {
                #pragma unroll
                for (int mg = 0; mg < 2; ++mg)
                    #pragma unroll
                    for (int ng = 0; ng < 4; ++ng)
                        #pragma unroll
                        for (int r = 0; r < 4; ++r) {
                            int kg = kt0 + ng * 16 + l15;
                            int qg = qw0 + mg * 16 + quad * 4 + r;
                            if (kg > qg) sc[mg][ng][r] = -1e30f;
                        }
            }

            // ---- online softmax (rows live across quad's 16-lane group) ----
            float al[2][4];
            #pragma unroll
            for (int mg = 0; mg < 2; ++mg)
                #pragma unroll
                for (int r = 0; r < 4; ++r) {
                    float mx = fmaxf(fmaxf(sc[mg][0][r], sc[mg][1][r]),
                                     fmaxf(sc[mg][2][r], sc[mg][3][r]));
                    mx = fmaxf(mx, __shfl_xor(mx, 1));
                    mx = fmaxf(mx, __shfl_xor(mx, 2));
                    mx = fmaxf(mx, __shfl_xor(mx, 4));
                    mx = fmaxf(mx, __shfl_xor(mx, 8));
                    float mnew = fmaxf(m_st[mg][r], mx);
                    float a = exp2f((m_st[mg][r] - mnew) * LOG2E);
                    m_st[mg][r] = mnew;
                    al[mg][r] = a;
                    float rs = 0.f;
                    #pragma unroll
                    for (int ng = 0; ng < 4; ++ng) {
                        float p = exp2f((sc[mg][ng][r] - mnew) * LOG2E);
                        sc[mg][ng][r] = p;
                        rs += p;
                    }
                    rs += __shfl_xor(rs, 1);
                    rs += __shfl_xor(rs, 2);
                    rs += __shfl_xor(rs, 4);
                    rs += __shfl_xor(rs, 8);
                    l_st[mg][r] = l_st[mg][r] * a + rs;
                }

            // ---- P -> LDS (C layout -> A layout round-trip) ----
            #pragma unroll
            for (int mg = 0; mg < 2; ++mg)
                #pragma unroll
                for (int ng = 0; ng < 4; ++ng)
                    #pragma unroll
                    for (int r = 0; r < 4; ++r)
                        Ps[w][mg * 16 + quad * 4 + r][ng * 16 + l15] =
                            __float2bfloat16(sc[mg][ng][r]);

            // ---- rescale accumulator ----
            #pragma unroll
            for (int mg = 0; mg < 2; ++mg)
                #pragma unroll
                for (int dg = 0; dg < 8; ++dg)
                    #pragma unroll
                    for (int r = 0; r < 4; ++r)
                        o[mg][dg][r] *= al[mg][r];

            // ---- O += P V ----
            #pragma unroll
            for (int kc = 0; kc < 2; ++kc) {
                bf16x8 pa0 = ld_frag(&Ps[w][l15][kc * 32 + quad * 8]);
                bf16x8 pa1 = ld_frag(&Ps[w][16 + l15][kc * 32 + quad * 8]);
                #pragma unroll
                for (int dg = 0; dg < 8; ++dg) {
                    bf16x8 vb = ld_frag(&Vs[dg * 16 + l15][kc * 32 + quad * 8]);
                    o[0][dg] = MFMA(pa0, vb, o[0][dg]);
                    o[1][dg] = MFMA(pa1, vb, o[1][dg]);
                }
            }
        }
    }

    // epilogue: O / l
    #pragma unroll
    for (int mg = 0; mg < 2; ++mg)
        #pragma unroll
        for (int r = 0; r < 4; ++r) {
            float inv = 1.0f / l_st[mg][r];
            #pragma unroll
            for (int dg = 0; dg < 8; ++dg)
                outb[(size_t)(qw0 + mg * 16 + quad * 4 + r) * HID +
                     h * HD + dg * 16 + l15] = __float2bfloat16(o[mg][dg][r] * inv);
        }
}

// ---------------------------------------------------------------------------
extern "C" void kernel_launch(void* const* d_in, const int* in_sizes, int n_in,
                              void* d_out, int out_size, void* d_ws, size_t ws_size,
                              hipStream_t stream) {
    const float* hidden = (const float*)d_in[0];
    const float* fcos   = (const float*)d_in[1];
    const float* fsin   = (const float*)d_in[2];
    // d_in[3] atten_mask: causal, applied analytically
    const float* Wq = (const float*)d_in[4];
    const float* Wk = (const float*)d_in[5];
    const float* Wv = (const float*)d_in[6];
    const float* Wo = (const float*)d_in[7];
    const float* qw = (const float*)d_in[8];
    const float* kw = (const float*)d_in[9];
    float* out = (float*)d_out;

    bf16* qkvb  = (bf16*)d_ws;                          // 2048 x 4096
    bf16* vT    = qkvb + (size_t)S_LEN * QKV_N;         // 1024 x 2048
    bf16* attnb = vT + (size_t)NKH * HD * S_LEN;        // 2048 x 2048
    bf16* wqkvb = attnb + (size_t)S_LEN * HID;          // 4096 x 2048
    bf16* hidb  = wqkvb + (size_t)QKV_N * HID;          // 2048 x 2048, reused for Wo_bf

    float* knew = out + (size_t)S_LEN * HID;
    float* vnew = knew + NKH * HD;

    int n4;
    n4 = S_LEN * HID / 4;
    cvt_bf16<<<n4 / 256, 256, 0, stream>>>(hidden, hidb, n4);
    n4 = NH * HD * HID / 4;
    cvt_bf16<<<n4 / 256, 256, 0, stream>>>(Wq, wqkvb, n4);
    n4 = NKH * HD * HID / 4;
    cvt_bf16<<<n4 / 256, 256, 0, stream>>>(Wk, wqkvb + (size_t)HID * HID, n4);
    cvt_bf16<<<n4 / 256, 256, 0, stream>>>(Wv, wqkvb + (size_t)(HID + NKH * HD) * HID, n4);

    // 1) fused QKV projection (bf16 out)
    gemm_bt<1><<<dim3(QKV_N / 128, S_LEN / 128), 256, 0, stream>>>(
        hidb, wqkvb, qkvb, S_LEN, QKV_N, HID);

    // Wo conversion into the (now dead) hidden_bf slot
    n4 = HID * HID / 4;
    cvt_bf16<<<n4 / 256, 256, 0, stream>>>(Wo, hidb, n4);

    // 2) RMSNorm + RoPE (+ SCALE folded into q) + k_new/v_new
    norm_rope<<<dim3(S_LEN, NH + NKH), 128, 0, stream>>>(
        qkvb, fcos, fsin, qw, kw, knew, vnew);

    // 3) v transpose for PV MFMA operand layout
    transpose_v<<<dim3((NKH * HD) / 64, S_LEN / 32), 256, 0, stream>>>(qkvb, vT);

    // 4) causal GQA flash attention (bf16 out)
    attn_mfma<<<dim3(S_LEN / 128, NH), 256, 0, stream>>>(qkvb, vT, attnb);

    // 5) output projection (fp32 out)
    gemm_bt<0><<<dim3(HID / 128, S_LEN / 128), 256, 0, stream>>>(
        attnb, hidb, out, S_LEN, HID, HID);
}

// Round 3
// 336.624 us; speedup vs baseline: 8.0427x; 1.4077x over previous
//
#include <hip/hip_runtime.h>
#include <hip/hip_bf16.h>
#include <math.h>

#define S_LEN 2048
#define HID 2048
#define NH 16
#define NKH 8
#define HD 128
#define QKV_N 4096
#define SCALE 0.08838834764831845f
#define EPS 1e-6f
#define LOG2E 1.4426950408889634f

typedef __hip_bfloat16 bf16;
typedef unsigned int u32;
typedef __bf16 bf16x8 __attribute__((ext_vector_type(8)));
typedef float f32x4 __attribute__((ext_vector_type(4)));

#define MFMA(a, b, c) __builtin_amdgcn_mfma_f32_16x16x32_bf16(a, b, c, 0, 0, 0)

static __device__ __forceinline__ bf16x8 ld_frag(const bf16* p) {
    return __builtin_bit_cast(bf16x8, *(const uint4*)p);
}

// async global->LDS, 16 B per lane. LDS dest = wave-uniform base + lane*16.
static __device__ __forceinline__ void gload_lds16(const void* g, void* l) {
    __builtin_amdgcn_global_load_lds(
        (const __attribute__((address_space(1))) u32*)g,
        (__attribute__((address_space(3))) u32*)l, 16, 0, 0);
}

// ---------------------------------------------------------------------------
// fp32 -> bf16 conversion
// ---------------------------------------------------------------------------
__global__ __launch_bounds__(256) void cvt_bf16(
    const float* __restrict__ src, bf16* __restrict__ dst, int n4)
{
    int i = blockIdx.x * 256 + threadIdx.x;
    if (i < n4) {
        float4 v = ((const float4*)src)[i];
        bf16* d = dst + 4 * (size_t)i;
        d[0] = __float2bfloat16(v.x);
        d[1] = __float2bfloat16(v.y);
        d[2] = __float2bfloat16(v.z);
        d[3] = __float2bfloat16(v.w);
    }
}

// ---------------------------------------------------------------------------
// m97-pattern bf16 MFMA GEMM: C = A * B^T. 128x128 tile, BK=32,
// global_load_lds width-16 staging, XOR-swizzled LDS columns.
// LDS layout per tile: [row][32] bf16, physical col-slot = logical ^ ((row>>1)&3).
// ---------------------------------------------------------------------------
template <int BF16OUT>
__global__ __launch_bounds__(256) void gemm_m97(
    const bf16* __restrict__ A, const bf16* __restrict__ B,
    void* __restrict__ Cv, int M, int N, int K)
{
    __shared__ bf16 As[128 * 32];
    __shared__ bf16 Bs[128 * 32];
    const int tid = threadIdx.x;
    const int n0 = blockIdx.x * 128, m0 = blockIdx.y * 128;
    const int w = tid >> 6, lane = tid & 63;
    const int l15 = lane & 15, quad = lane >> 4;
    const int wr = (w >> 1) * 64, wc = (w & 1) * 64;

    f32x4 acc[4][4];
    #pragma unroll
    for (int i = 0; i < 4; ++i)
        #pragma unroll
        for (int j = 0; j < 4; ++j)
            acc[i][j] = f32x4{0.f, 0.f, 0.f, 0.f};

    // staging: lane -> row 16c+(lane>>2), phys slot lane&3,
    // global logical slot = (lane&3) ^ ((lane>>3)&3)
    const int grow = lane >> 2;
    const int gcol = ((lane & 3) ^ ((lane >> 3) & 3)) * 8;
    // fragment read: logical slot = quad, phys = quad ^ ((l15>>1)&3)
    const int fcol = (quad ^ ((l15 >> 1) & 3)) * 8;

    for (int k0 = 0; k0 < K; k0 += 32) {
        __syncthreads();                       // prev compute done
        #pragma unroll
        for (int j = 0; j < 2; ++j) {
            int c = 2 * w + j;
            int row = 16 * c + grow;
            gload_lds16(A + (size_t)(m0 + row) * K + k0 + gcol, &As[c * 512]);
            gload_lds16(B + (size_t)(n0 + row) * K + k0 + gcol, &Bs[c * 512]);
        }
        __syncthreads();                       // drains vmcnt -> tiles ready

        bf16x8 av[4], bv[4];
        #pragma unroll
        for (int i = 0; i < 4; ++i)
            av[i] = ld_frag(&As[(wr + i * 16 + l15) * 32 + fcol]);
        #pragma unroll
        for (int j = 0; j < 4; ++j)
            bv[j] = ld_frag(&Bs[(wc + j * 16 + l15) * 32 + fcol]);
        #pragma unroll
        for (int i = 0; i < 4; ++i)
            #pragma unroll
            for (int j = 0; j < 4; ++j)
                acc[i][j] = MFMA(av[i], bv[j], acc[i][j]);
    }

    #pragma unroll
    for (int i = 0; i < 4; ++i)
        #pragma unroll
        for (int j = 0; j < 4; ++j)
            #pragma unroll
            for (int r = 0; r < 4; ++r) {
                int row = m0 + wr + i * 16 + quad * 4 + r;
                int col = n0 + wc + j * 16 + l15;
                if (BF16OUT)
                    ((bf16*)Cv)[(size_t)row * N + col] = __float2bfloat16(acc[i][j][r]);
                else
                    ((float*)Cv)[(size_t)row * N + col] = acc[i][j][r];
            }
}

// ---------------------------------------------------------------------------
// RMSNorm + RoPE in place on bf16 qkv. q rows pre-scaled by SCALE.
// ---------------------------------------------------------------------------
__global__ __launch_bounds__(128) void norm_rope(
    bf16* __restrict__ qkvb,
    const float* __restrict__ cosb, const float* __restrict__ sinb,
    const float* __restrict__ qw, const float* __restrict__ kw,
    float* __restrict__ knew, float* __restrict__ vnew)
{
    const int s = blockIdx.x;
    const int h = blockIdx.y;
    const int d = threadIdx.x;

    bf16* row;
    const float* wgt;
    int kh = -1;
    if (h < NH) {
        row = qkvb + (size_t)s * QKV_N + h * HD;
        wgt = qw;
    } else {
        kh = h - NH;
        row = qkvb + (size_t)s * QKV_N + HID + kh * HD;
        wgt = kw;
    }

    float x = __bfloat162float(row[d]);
    float ss = x * x;
    #pragma unroll
    for (int off = 32; off >= 1; off >>= 1) ss += __shfl_xor(ss, off, 64);

    __shared__ float sred[2];
    __shared__ float xn[128];
    int lane = d & 63, wid = d >> 6;
    if (lane == 0) sred[wid] = ss;
    __syncthreads();
    float total = sred[0] + sred[1];
    float rr = rsqrtf(total * (1.0f / 128.0f) + EPS);
    xn[d] = x * rr * wgt[d];
    __syncthreads();

    float res;
    if (d < 64) {
        float c = cosb[s * 64 + d], sn = sinb[s * 64 + d];
        res = xn[d] * c - xn[d + 64] * sn;
    } else {
        int d2 = d - 64;
        float c = cosb[s * 64 + d2], sn = sinb[s * 64 + d2];
        res = xn[d2] * sn + xn[d] * c;
    }

    float store_val = (h < NH) ? res * SCALE : res;
    row[d] = __float2bfloat16(store_val);

    if (kh >= 0 && s == S_LEN - 1) {
        knew[kh * HD + d] = res;
        vnew[kh * HD + d] =
            __bfloat162float(qkvb[(size_t)s * QKV_N + HID + NKH * HD + kh * HD + d]);
    }
}

// ---------------------------------------------------------------------------
// v transpose: qkv v-part [s][r] -> vT[r][s]
// ---------------------------------------------------------------------------
__global__ __launch_bounds__(256) void transpose_v(
    const bf16* __restrict__ qkvb, bf16* __restrict__ vT)
{
    const int r0 = blockIdx.x * 64;
    const int s0 = blockIdx.y * 32;
    const int rl = threadIdx.x & 63, sg = threadIdx.x >> 6;

    union { uint4 u; bf16 b[8]; } pk;
    #pragma unroll
    for (int j = 0; j < 8; ++j)
        pk.b[j] = qkvb[(size_t)(s0 + sg * 8 + j) * QKV_N + HID + NKH * HD + r0 + rl];
    *(uint4*)(vT + (size_t)(r0 + rl) * S_LEN + s0 + sg * 8) = pk.u;
}

// ---------------------------------------------------------------------------
// Flash attention v3: transposed-S scheme, async double-buffered staging.
// grid (32 qb-tiles of 64 rows [interleaved heavy/light], 16 heads),
// 128 threads = 2 waves; wave w owns 32 q-rows (2 n-groups of 16).
// S^T = MFMA(K_frag, Q_frag): lane l15 = q-col, regs = k-rows ->
// softmax row = 16 regs in-lane + 2 shuffles. O^T = MFMA(V^T_frag, P^T_frag).
// K/V staged by global_load_lds (wave0: K, wave1: V) with XOR col swizzle.
// ---------------------------------------------------------------------------
__global__ __launch_bounds__(128) void attn_mfma(
    const bf16* __restrict__ qkvb, const bf16* __restrict__ vT,
    bf16* __restrict__ outb)
{
    __shared__ bf16 Ks[2][64 * 128];
    __shared__ bf16 Vs[2][128 * 64];
    __shared__ bf16 Ps[2][32 * 72];

    const int x = blockIdx.x;
    const int qb = (x & 1) ? (31 - (x >> 1)) : (x >> 1);   // heavy/light interleave
    const int h = blockIdx.y, kvh = h >> 1;
    const int tid = threadIdx.x, w = tid >> 6, lane = tid & 63;
    const int l15 = lane & 15, quad = lane >> 4;
    const int qt0 = qb * 64;
    const int qw0 = qt0 + w * 32;

    // Q fragments (B-operand layout == A layout): [n=q(l15)][k=d(quad*8+j)]
    bf16x8 qf[2][4];
    #pragma unroll
    for (int ng = 0; ng < 2; ++ng)
        #pragma unroll
        for (int dk = 0; dk < 4; ++dk)
            qf[ng][dk] = ld_frag(qkvb + (size_t)(qw0 + ng * 16 + l15) * QKV_N +
                                 h * HD + dk * 32 + quad * 8);

    f32x4 o[8][2];
    #pragma unroll
    for (int dt = 0; dt < 8; ++dt)
        #pragma unroll
        for (int ng = 0; ng < 2; ++ng)
            o[dt][ng] = f32x4{0.f, 0.f, 0.f, 0.f};

    float m_st[2] = {-1e30f, -1e30f}, l_st[2] = {0.f, 0.f};

    // ---- staging lambda (wave-uniform roles; per-lane global addrs) ----
    auto stage = [&](int t, int nb) {
        const int kt0 = t * 64;
        if (w == 0) {
            // K tile [64][128]: call c covers 4 rows; phys slot lane&15,
            // logical = phys ^ (row&15)
            #pragma unroll
            for (int c = 0; c < 16; ++c) {
                int row = 4 * c + (lane >> 4);
                int ls = (lane & 15) ^ (row & 15);
                gload_lds16(qkvb + (size_t)(kt0 + row) * QKV_N + HID +
                            kvh * HD + ls * 8,
                            &Ks[nb][c * 512]);
            }
        } else {
            // V^T tile [128][64]: call c covers 8 rows; phys slot lane&7,
            // logical = phys ^ (row&7) = (lane&7) ^ ((lane>>3)&7)
            #pragma unroll
            for (int c = 0; c < 16; ++c) {
                int row = 8 * c + (lane >> 3);
                int ls = (lane & 7) ^ ((lane >> 3) & 7);
                gload_lds16(vT + (size_t)(kvh * HD + row) * S_LEN + kt0 + ls * 8,
                            &Vs[nb][c * 512]);
            }
        }
    };

    stage(0, 0);

    for (int t = 0; t <= qb; ++t) {
        const int pp = t & 1;
        const int kt0 = t * 64;
        __syncthreads();                 // drains stage(t); all waves past buf[1-pp]
        if (t < qb) stage(t + 1, pp ^ 1);

        // ---- S^T = K Q^T : D[m=k][n=q] ----
        f32x4 sc[4][2];
        #pragma unroll
        for (int mt = 0; mt < 4; ++mt)
            #pragma unroll
            for (int ng = 0; ng < 2; ++ng)
                sc[mt][ng] = f32x4{0.f, 0.f, 0.f, 0.f};
        #pragma unroll
        for (int dk = 0; dk < 4; ++dk)
            #pragma unroll
            for (int mt = 0; mt < 4; ++mt) {
                bf16x8 kf = ld_frag(&Ks[pp][(mt * 16 + l15) * 128 +
                                            (((dk * 4 + quad) ^ l15) * 8)]);
                sc[mt][0] = MFMA(kf, qf[0][dk], sc[mt][0]);
                sc[mt][1] = MFMA(kf, qf[1][dk], sc[mt][1]);
            }

        // ---- causal mask (only diagonal tile) ----
        if (t == qb) {
            #pragma unroll
            for (int mt = 0; mt < 4; ++mt)
                #pragma unroll
                for (int ng = 0; ng < 2; ++ng)
                    #pragma unroll
                    for (int r = 0; r < 4; ++r) {
                        int kg = kt0 + mt * 16 + quad * 4 + r;
                        int qg = qw0 + ng * 16 + l15;
                        if (kg > qg) sc[mt][ng][r] = -1e30f;
                    }
        }

        // ---- online softmax: per-lane 16-reg reduce + 2 shuffles ----
        float al[2];
        #pragma unroll
        for (int ng = 0; ng < 2; ++ng) {
            float mx = -1e30f;
            #pragma unroll
            for (int mt = 0; mt < 4; ++mt)
                #pragma unroll
                for (int r = 0; r < 4; ++r)
                    mx = fmaxf(mx, sc[mt][ng][r]);
            mx = fmaxf(mx, __shfl_xor(mx, 16, 64));
            mx = fmaxf(mx, __shfl_xor(mx, 32, 64));
            float mnew = fmaxf(m_st[ng], mx);
            float a = exp2f((m_st[ng] - mnew) * LOG2E);
            m_st[ng] = mnew;
            al[ng] = a;
            float rs = 0.f;
            #pragma unroll
            for (int mt = 0; mt < 4; ++mt) {
                union { uint2 u; bf16 hh[4]; } pk;
                #pragma unroll
                for (int r = 0; r < 4; ++r) {
                    float p = exp2f((sc[mt][ng][r] - mnew) * LOG2E);
                    pk.hh[r] = __float2bfloat16(p);
                    rs += p;
                }
                // P^T store -> Ps[q_local][k_local], k contiguous (b64)
                *(uint2*)&Ps[w][(ng * 16 + l15) * 72 + mt * 16 + quad * 4] = pk.u;
            }
            rs += __shfl_xor(rs, 16, 64);
            rs += __shfl_xor(rs, 32, 64);
            l_st[ng] = l_st[ng] * a + rs;
        }

        // ---- rescale O ----
        #pragma unroll
        for (int dt = 0; dt < 8; ++dt)
            #pragma unroll
            for (int ng = 0; ng < 2; ++ng)
                #pragma unroll
                for (int r = 0; r < 4; ++r)
                    o[dt][ng][r] *= al[ng];

        // ---- O^T += V^T P^T ----
        #pragma unroll
        for (int kc = 0; kc < 2; ++kc) {
            bf16x8 pf0 = ld_frag(&Ps[w][l15 * 72 + kc * 32 + quad * 8]);
            bf16x8 pf1 = ld_frag(&Ps[w][(16 + l15) * 72 + kc * 32 + quad * 8]);
            #pragma unroll
            for (int dt = 0; dt < 8; ++dt) {
                bf16x8 vf = ld_frag(&Vs[pp][(dt * 16 + l15) * 64 +
                                            (((kc * 4 + quad) ^ (l15 & 7)) * 8)]);
                o[dt][0] = MFMA(vf, pf0, o[dt][0]);
                o[dt][1] = MFMA(vf, pf1, o[dt][1]);
            }
        }
    }

    // ---- epilogue: O^T / l -> out (8 B packed stores) ----
    #pragma unroll
    for (int ng = 0; ng < 2; ++ng) {
        float inv = 1.0f / l_st[ng];
        int qg = qw0 + ng * 16 + l15;
        #pragma unroll
        for (int dt = 0; dt < 8; ++dt) {
            union { uint2 u; bf16 hh[4]; } pk;
            #pragma unroll
            for (int r = 0; r < 4; ++r)
                pk.hh[r] = __float2bfloat16(o[dt][ng][r] * inv);
            *(uint2*)&outb[(size_t)qg * HID + h * HD + dt * 16 + quad * 4] = pk.u;
        }
    }
}

// ---------------------------------------------------------------------------
extern "C" void kernel_launch(void* const* d_in, const int* in_sizes, int n_in,
                              void* d_out, int out_size, void* d_ws, size_t ws_size,
                              hipStream_t stream) {
    const float* hidden = (const float*)d_in[0];
    const float* fcos   = (const float*)d_in[1];
    const float* fsin   = (const float*)d_in[2];
    // d_in[3] atten_mask: causal, applied analytically
    const float* Wq = (const float*)d_in[4];
    const float* Wk = (const float*)d_in[5];
    const float* Wv = (const float*)d_in[6];
    const float* Wo = (const float*)d_in[7];
    const float* qw = (const float*)d_in[8];
    const float* kw = (const float*)d_in[9];
    float* out = (float*)d_out;

    bf16* qkvb  = (bf16*)d_ws;                          // 2048 x 4096
    bf16* vT    = qkvb + (size_t)S_LEN * QKV_N;         // 1024 x 2048
    bf16* attnb = vT + (size_t)NKH * HD * S_LEN;        // 2048 x 2048
    bf16* wqkvb = attnb + (size_t)S_LEN * HID;          // 4096 x 2048
    bf16* hidb  = wqkvb + (size_t)QKV_N * HID;          // 2048 x 2048, reused for Wo_bf

    float* knew = out + (size_t)S_LEN * HID;
    float* vnew = knew + NKH * HD;

    int n4;
    n4 = S_LEN * HID / 4;
    cvt_bf16<<<n4 / 256, 256, 0, stream>>>(hidden, hidb, n4);
    n4 = NH * HD * HID / 4;
    cvt_bf16<<<n4 / 256, 256, 0, stream>>>(Wq, wqkvb, n4);
    n4 = NKH * HD * HID / 4;
    cvt_bf16<<<n4 / 256, 256, 0, stream>>>(Wk, wqkvb + (size_t)HID * HID, n4);
    cvt_bf16<<<n4 / 256, 256, 0, stream>>>(Wv, wqkvb + (size_t)(HID + NKH * HD) * HID, n4);

    // 1) fused QKV projection (bf16 out)
    gemm_m97<1><<<dim3(QKV_N / 128, S_LEN / 128), 256, 0, stream>>>(
        hidb, wqkvb, qkvb, S_LEN, QKV_N, HID);

    // Wo conversion into the (now dead) hidden_bf slot
    n4 = HID * HID / 4;
    cvt_bf16<<<n4 / 256, 256, 0, stream>>>(Wo, hidb, n4);

    // 2) RMSNorm + RoPE (+ SCALE folded into q) + k_new/v_new
    norm_rope<<<dim3(S_LEN, NH + NKH), 128, 0, stream>>>(
        qkvb, fcos, fsin, qw, kw, knew, vnew);

    // 3) v transpose for PV MFMA operand layout
    transpose_v<<<dim3((NKH * HD) / 64, S_LEN / 32), 256, 0, stream>>>(qkvb, vT);

    // 4) causal GQA flash attention (bf16 out)
    attn_mfma<<<dim3(32, NH), 128, 0, stream>>>(qkvb, vT, attnb);

    // 5) output projection (fp32 out)
    gemm_m97<0><<<dim3(HID / 128, S_LEN / 128), 256, 0, stream>>>(
        attnb, hidb, out, S_LEN, HID, HID);
}

// Round 4
// 293.591 us; speedup vs baseline: 9.2215x; 1.1466x over previous
//
#include <hip/hip_runtime.h>
#include <hip/hip_bf16.h>
#include <math.h>

#define S_LEN 2048
#define HID 2048
#define NH 16
#define NKH 8
#define HD 128
#define QKV_N 4096
#define SCALE 0.08838834764831845f
#define EPS 1e-6f
#define LOG2E 1.4426950408889634f

typedef __hip_bfloat16 bf16;
typedef unsigned int u32;
typedef __bf16 bf16x8 __attribute__((ext_vector_type(8)));
typedef float f32x4 __attribute__((ext_vector_type(4)));

#define MFMA(a, b, c) __builtin_amdgcn_mfma_f32_16x16x32_bf16(a, b, c, 0, 0, 0)

static __device__ __forceinline__ bf16x8 ld_frag(const bf16* p) {
    return __builtin_bit_cast(bf16x8, *(const uint4*)p);
}

// async global->LDS, 16 B per lane. LDS dest = wave-uniform base + lane*16.
static __device__ __forceinline__ void gload_lds16(const void* g, void* l) {
    __builtin_amdgcn_global_load_lds(
        (const __attribute__((address_space(1))) u32*)g,
        (__attribute__((address_space(3))) u32*)l, 16, 0, 0);
}

// ---------------------------------------------------------------------------
// merged fp32 -> bf16 conversion: hidden | Wq | Wk | Wv in one launch.
// n4 thresholds (float4 units): 1M | 2M | 2.5M | 3M. grid = 12288 x 256.
// ---------------------------------------------------------------------------
__global__ __launch_bounds__(256) void cvt4(
    const float* __restrict__ s0, const float* __restrict__ s1,
    const float* __restrict__ s2, const float* __restrict__ s3,
    bf16* __restrict__ d0, bf16* __restrict__ d1,
    bf16* __restrict__ d2, bf16* __restrict__ d3)
{
    int i = blockIdx.x * 256 + threadIdx.x;
    const float* s; bf16* d; int off;
    if (i < (1 << 20))                   { s = s0; d = d0; off = 0; }
    else if (i < (2 << 20))              { s = s1; d = d1; off = 1 << 20; }
    else if (i < (2 << 20) + (1 << 19))  { s = s2; d = d2; off = 2 << 20; }
    else                                 { s = s3; d = d3; off = (2 << 20) + (1 << 19); }
    int j = i - off;
    float4 v = ((const float4*)s)[j];
    bf16* p = d + 4 * (size_t)j;
    p[0] = __float2bfloat16(v.x);
    p[1] = __float2bfloat16(v.y);
    p[2] = __float2bfloat16(v.z);
    p[3] = __float2bfloat16(v.w);
}

__global__ __launch_bounds__(256) void cvt_bf16(
    const float* __restrict__ src, bf16* __restrict__ dst, int n4)
{
    int i = blockIdx.x * 256 + threadIdx.x;
    if (i < n4) {
        float4 v = ((const float4*)src)[i];
        bf16* d = dst + 4 * (size_t)i;
        d[0] = __float2bfloat16(v.x);
        d[1] = __float2bfloat16(v.y);
        d[2] = __float2bfloat16(v.z);
        d[3] = __float2bfloat16(v.w);
    }
}

// ---------------------------------------------------------------------------
// m97-pattern bf16 MFMA GEMM: C = A * B^T. 128x128 tile, BK=32,
// global_load_lds width-16 staging, XOR-swizzled LDS columns.
// ---------------------------------------------------------------------------
template <int BF16OUT>
__global__ __launch_bounds__(256) void gemm_m97(
    const bf16* __restrict__ A, const bf16* __restrict__ B,
    void* __restrict__ Cv, int M, int N, int K)
{
    __shared__ bf16 As[128 * 32];
    __shared__ bf16 Bs[128 * 32];
    const int tid = threadIdx.x;
    const int n0 = blockIdx.x * 128, m0 = blockIdx.y * 128;
    const int w = tid >> 6, lane = tid & 63;
    const int l15 = lane & 15, quad = lane >> 4;
    const int wr = (w >> 1) * 64, wc = (w & 1) * 64;

    f32x4 acc[4][4];
    #pragma unroll
    for (int i = 0; i < 4; ++i)
        #pragma unroll
        for (int j = 0; j < 4; ++j)
            acc[i][j] = f32x4{0.f, 0.f, 0.f, 0.f};

    const int grow = lane >> 2;
    const int gcol = ((lane & 3) ^ ((lane >> 3) & 3)) * 8;
    const int fcol = (quad ^ ((l15 >> 1) & 3)) * 8;

    for (int k0 = 0; k0 < K; k0 += 32) {
        __syncthreads();
        #pragma unroll
        for (int j = 0; j < 2; ++j) {
            int c = 2 * w + j;
            int row = 16 * c + grow;
            gload_lds16(A + (size_t)(m0 + row) * K + k0 + gcol, &As[c * 512]);
            gload_lds16(B + (size_t)(n0 + row) * K + k0 + gcol, &Bs[c * 512]);
        }
        __syncthreads();

        bf16x8 av[4], bv[4];
        #pragma unroll
        for (int i = 0; i < 4; ++i)
            av[i] = ld_frag(&As[(wr + i * 16 + l15) * 32 + fcol]);
        #pragma unroll
        for (int j = 0; j < 4; ++j)
            bv[j] = ld_frag(&Bs[(wc + j * 16 + l15) * 32 + fcol]);
        #pragma unroll
        for (int i = 0; i < 4; ++i)
            #pragma unroll
            for (int j = 0; j < 4; ++j)
                acc[i][j] = MFMA(av[i], bv[j], acc[i][j]);
    }

    #pragma unroll
    for (int i = 0; i < 4; ++i)
        #pragma unroll
        for (int j = 0; j < 4; ++j)
            #pragma unroll
            for (int r = 0; r < 4; ++r) {
                int row = m0 + wr + i * 16 + quad * 4 + r;
                int col = n0 + wc + j * 16 + l15;
                if (BF16OUT)
                    ((bf16*)Cv)[(size_t)row * N + col] = __float2bfloat16(acc[i][j][r]);
                else
                    ((float*)Cv)[(size_t)row * N + col] = acc[i][j][r];
            }
}

// ---------------------------------------------------------------------------
// 128(M)x64(N)-tile variant, fp32 out — for the 2048x2048 out-projection
// (512 blocks -> 2/CU). Wave w owns rows w*32..+31, all 64 cols.
// ---------------------------------------------------------------------------
__global__ __launch_bounds__(256, 3) void gemm_n64(
    const bf16* __restrict__ A, const bf16* __restrict__ B,
    float* __restrict__ C, int M, int N, int K)
{
    __shared__ bf16 As[128 * 32];
    __shared__ bf16 Bs[64 * 32];
    const int tid = threadIdx.x;
    const int n0 = blockIdx.x * 64, m0 = blockIdx.y * 128;
    const int w = tid >> 6, lane = tid & 63;
    const int l15 = lane & 15, quad = lane >> 4;

    f32x4 acc[2][4];
    #pragma unroll
    for (int i = 0; i < 2; ++i)
        #pragma unroll
        for (int j = 0; j < 4; ++j)
            acc[i][j] = f32x4{0.f, 0.f, 0.f, 0.f};

    const int grow = lane >> 2;
    const int gcol = ((lane & 3) ^ ((lane >> 3) & 3)) * 8;
    const int fcol = (quad ^ ((l15 >> 1) & 3)) * 8;

    for (int k0 = 0; k0 < K; k0 += 32) {
        __syncthreads();
        #pragma unroll
        for (int j = 0; j < 3; ++j) {
            int c = 3 * w + j;                 // 0..11: 8 A-chunks, 4 B-chunks
            if (c < 8) {
                int row = 16 * c + grow;
                gload_lds16(A + (size_t)(m0 + row) * K + k0 + gcol, &As[c * 512]);
            } else {
                int row = 16 * (c - 8) + grow;
                gload_lds16(B + (size_t)(n0 + row) * K + k0 + gcol, &Bs[(c - 8) * 512]);
            }
        }
        __syncthreads();

        bf16x8 av[2], bv[4];
        #pragma unroll
        for (int i = 0; i < 2; ++i)
            av[i] = ld_frag(&As[(w * 32 + i * 16 + l15) * 32 + fcol]);
        #pragma unroll
        for (int j = 0; j < 4; ++j)
            bv[j] = ld_frag(&Bs[(j * 16 + l15) * 32 + fcol]);
        #pragma unroll
        for (int i = 0; i < 2; ++i)
            #pragma unroll
            for (int j = 0; j < 4; ++j)
                acc[i][j] = MFMA(av[i], bv[j], acc[i][j]);
    }

    #pragma unroll
    for (int i = 0; i < 2; ++i)
        #pragma unroll
        for (int j = 0; j < 4; ++j)
            #pragma unroll
            for (int r = 0; r < 4; ++r)
                C[(size_t)(m0 + w * 32 + i * 16 + quad * 4 + r) * N +
                  n0 + j * 16 + l15] = acc[i][j][r];
}

// ---------------------------------------------------------------------------
// RMSNorm + RoPE in place on bf16 qkv. q rows pre-scaled by SCALE.
// ---------------------------------------------------------------------------
__global__ __launch_bounds__(128) void norm_rope(
    bf16* __restrict__ qkvb,
    const float* __restrict__ cosb, const float* __restrict__ sinb,
    const float* __restrict__ qw, const float* __restrict__ kw,
    float* __restrict__ knew, float* __restrict__ vnew)
{
    const int s = blockIdx.x;
    const int h = blockIdx.y;
    const int d = threadIdx.x;

    bf16* row;
    const float* wgt;
    int kh = -1;
    if (h < NH) {
        row = qkvb + (size_t)s * QKV_N + h * HD;
        wgt = qw;
    } else {
        kh = h - NH;
        row = qkvb + (size_t)s * QKV_N + HID + kh * HD;
        wgt = kw;
    }

    float x = __bfloat162float(row[d]);
    float ss = x * x;
    #pragma unroll
    for (int off = 32; off >= 1; off >>= 1) ss += __shfl_xor(ss, off, 64);

    __shared__ float sred[2];
    __shared__ float xn[128];
    int lane = d & 63, wid = d >> 6;
    if (lane == 0) sred[wid] = ss;
    __syncthreads();
    float total = sred[0] + sred[1];
    float rr = rsqrtf(total * (1.0f / 128.0f) + EPS);
    xn[d] = x * rr * wgt[d];
    __syncthreads();

    float res;
    if (d < 64) {
        float c = cosb[s * 64 + d], sn = sinb[s * 64 + d];
        res = xn[d] * c - xn[d + 64] * sn;
    } else {
        int d2 = d - 64;
        float c = cosb[s * 64 + d2], sn = sinb[s * 64 + d2];
        res = xn[d2] * sn + xn[d] * c;
    }

    float store_val = (h < NH) ? res * SCALE : res;
    row[d] = __float2bfloat16(store_val);

    if (kh >= 0 && s == S_LEN - 1) {
        knew[kh * HD + d] = res;
        vnew[kh * HD + d] =
            __bfloat162float(qkvb[(size_t)s * QKV_N + HID + NKH * HD + kh * HD + d]);
    }
}

// ---------------------------------------------------------------------------
// v transpose: qkv v-part [s][r] -> vT[r][s]
// ---------------------------------------------------------------------------
__global__ __launch_bounds__(256) void transpose_v(
    const bf16* __restrict__ qkvb, bf16* __restrict__ vT)
{
    const int r0 = blockIdx.x * 64;
    const int s0 = blockIdx.y * 32;
    const int rl = threadIdx.x & 63, sg = threadIdx.x >> 6;

    union { uint4 u; bf16 b[8]; } pk;
    #pragma unroll
    for (int j = 0; j < 8; ++j)
        pk.b[j] = qkvb[(size_t)(s0 + sg * 8 + j) * QKV_N + HID + NKH * HD + r0 + rl];
    *(uint4*)(vT + (size_t)(r0 + rl) * S_LEN + s0 + sg * 8) = pk.u;
}

// ---------------------------------------------------------------------------
// Flash attention v4: transposed-S, async dbuf staging, 4 waves x 16 q-rows.
// grid (32, 16) = 512 blocks x 256 thr; LDS 74752 B -> 2 blocks/CU = 8 waves.
// qb mapping flipped for h>=8 so co-resident blocks pair heavy with light.
// ---------------------------------------------------------------------------
__global__ __launch_bounds__(256, 2) void attn_mfma(
    const bf16* __restrict__ qkvb, const bf16* __restrict__ vT,
    bf16* __restrict__ outb)
{
    __shared__ bf16 Ks[2][64 * 128];
    __shared__ bf16 Vs[2][128 * 64];
    __shared__ bf16 Ps[4][16 * 72];

    const int x = blockIdx.x;
    const int h = blockIdx.y, kvh = h >> 1;
    int a = (x & 1) ? (31 - (x >> 1)) : (x >> 1);
    const int qb = (h < 8) ? a : 31 - a;
    const int tid = threadIdx.x, w = tid >> 6, lane = tid & 63;
    const int l15 = lane & 15, quad = lane >> 4;
    const int qw0 = qb * 64 + w * 16;          // this wave's 16 q-rows

    bf16x8 qf[4];
    #pragma unroll
    for (int dk = 0; dk < 4; ++dk)
        qf[dk] = ld_frag(qkvb + (size_t)(qw0 + l15) * QKV_N +
                         h * HD + dk * 32 + quad * 8);

    f32x4 o[8];
    #pragma unroll
    for (int dt = 0; dt < 8; ++dt) o[dt] = f32x4{0.f, 0.f, 0.f, 0.f};
    float m_st = -1e30f, l_st = 0.f;

    auto stage = [&](int t, int nb) {
        const int kt0 = t * 64;
        if (w < 2) {
            #pragma unroll
            for (int c = 0; c < 8; ++c) {
                int chunk = w * 8 + c;
                int row = 4 * chunk + (lane >> 4);
                int ls = (lane & 15) ^ (row & 15);
                gload_lds16(qkvb + (size_t)(kt0 + row) * QKV_N + HID +
                            kvh * HD + ls * 8,
                            &Ks[nb][chunk * 512]);
            }
        } else {
            #pragma unroll
            for (int c = 0; c < 8; ++c) {
                int chunk = (w - 2) * 8 + c;
                int row = 8 * chunk + (lane >> 3);
                int ls = (lane & 7) ^ ((lane >> 3) & 7);
                gload_lds16(vT + (size_t)(kvh * HD + row) * S_LEN + kt0 + ls * 8,
                            &Vs[nb][chunk * 512]);
            }
        }
    };

    stage(0, 0);

    for (int t = 0; t <= qb; ++t) {
        const int pp = t & 1;
        __syncthreads();
        if (t < qb) stage(t + 1, pp ^ 1);

        // ---- S^T = K Q^T ----
        f32x4 sc[4];
        #pragma unroll
        for (int mt = 0; mt < 4; ++mt) sc[mt] = f32x4{0.f, 0.f, 0.f, 0.f};
        #pragma unroll
        for (int dk = 0; dk < 4; ++dk)
            #pragma unroll
            for (int mt = 0; mt < 4; ++mt) {
                bf16x8 kf = ld_frag(&Ks[pp][(mt * 16 + l15) * 128 +
                                            (((dk * 4 + quad) ^ l15) * 8)]);
                sc[mt] = MFMA(kf, qf[dk], sc[mt]);
            }

        if (t == qb) {
            #pragma unroll
            for (int mt = 0; mt < 4; ++mt)
                #pragma unroll
                for (int r = 0; r < 4; ++r) {
                    int kg = t * 64 + mt * 16 + quad * 4 + r;
                    if (kg > qw0 + l15) sc[mt][r] = -1e30f;
                }
        }

        // ---- online softmax ----
        float mx = -1e30f;
        #pragma unroll
        for (int mt = 0; mt < 4; ++mt)
            #pragma unroll
            for (int r = 0; r < 4; ++r) mx = fmaxf(mx, sc[mt][r]);
        mx = fmaxf(mx, __shfl_xor(mx, 16, 64));
        mx = fmaxf(mx, __shfl_xor(mx, 32, 64));
        float mnew = fmaxf(m_st, mx);
        float al = exp2f((m_st - mnew) * LOG2E);
        m_st = mnew;
        float rs = 0.f;
        #pragma unroll
        for (int mt = 0; mt < 4; ++mt) {
            union { uint2 u; bf16 hh[4]; } pk;
            #pragma unroll
            for (int r = 0; r < 4; ++r) {
                float p = exp2f((sc[mt][r] - mnew) * LOG2E);
                pk.hh[r] = __float2bfloat16(p);
                rs += p;
            }
            *(uint2*)&Ps[w][l15 * 72 + mt * 16 + quad * 4] = pk.u;
        }
        rs += __shfl_xor(rs, 16, 64);
        rs += __shfl_xor(rs, 32, 64);
        l_st = l_st * al + rs;

        #pragma unroll
        for (int dt = 0; dt < 8; ++dt)
            #pragma unroll
            for (int r = 0; r < 4; ++r) o[dt][r] *= al;

        // ---- O^T += V^T P^T ----
        #pragma unroll
        for (int kc = 0; kc < 2; ++kc) {
            bf16x8 pf = ld_frag(&Ps[w][l15 * 72 + kc * 32 + quad * 8]);
            #pragma unroll
            for (int dt = 0; dt < 8; ++dt) {
                bf16x8 vf = ld_frag(&Vs[pp][(dt * 16 + l15) * 64 +
                                            (((kc * 4 + quad) ^ (l15 & 7)) * 8)]);
                o[dt] = MFMA(vf, pf, o[dt]);
            }
        }
    }

    float inv = 1.0f / l_st;
    int qg = qw0 + l15;
    #pragma unroll
    for (int dt = 0; dt < 8; ++dt) {
        union { uint2 u; bf16 hh[4]; } pk;
        #pragma unroll
        for (int r = 0; r < 4; ++r)
            pk.hh[r] = __float2bfloat16(o[dt][r] * inv);
        *(uint2*)&outb[(size_t)qg * HID + h * HD + dt * 16 + quad * 4] = pk.u;
    }
}

// ---------------------------------------------------------------------------
extern "C" void kernel_launch(void* const* d_in, const int* in_sizes, int n_in,
                              void* d_out, int out_size, void* d_ws, size_t ws_size,
                              hipStream_t stream) {
    const float* hidden = (const float*)d_in[0];
    const float* fcos   = (const float*)d_in[1];
    const float* fsin   = (const float*)d_in[2];
    // d_in[3] atten_mask: causal, applied analytically
    const float* Wq = (const float*)d_in[4];
    const float* Wk = (const float*)d_in[5];
    const float* Wv = (const float*)d_in[6];
    const float* Wo = (const float*)d_in[7];
    const float* qw = (const float*)d_in[8];
    const float* kw = (const float*)d_in[9];
    float* out = (float*)d_out;

    bf16* qkvb  = (bf16*)d_ws;                          // 2048 x 4096
    bf16* vT    = qkvb + (size_t)S_LEN * QKV_N;         // 1024 x 2048
    bf16* attnb = vT + (size_t)NKH * HD * S_LEN;        // 2048 x 2048
    bf16* wqkvb = attnb + (size_t)S_LEN * HID;          // 4096 x 2048
    bf16* hidb  = wqkvb + (size_t)QKV_N * HID;          // 2048 x 2048, reused for Wo_bf

    float* knew = out + (size_t)S_LEN * HID;
    float* vnew = knew + NKH * HD;

    // 0) merged conversions: hidden, Wq, Wk, Wv  (3M float4 units -> 12288 blocks)
    cvt4<<<12288, 256, 0, stream>>>(
        hidden, Wq, Wk, Wv,
        hidb, wqkvb, wqkvb + (size_t)HID * HID,
        wqkvb + (size_t)(HID + NKH * HD) * HID);

    // 1) fused QKV projection (bf16 out)
    gemm_m97<1><<<dim3(QKV_N / 128, S_LEN / 128), 256, 0, stream>>>(
        hidb, wqkvb, qkvb, S_LEN, QKV_N, HID);

    // Wo conversion into the (now dead) hidden_bf slot
    cvt_bf16<<<(HID * HID / 4) / 256, 256, 0, stream>>>(Wo, hidb, HID * HID / 4);

    // 2) RMSNorm + RoPE (+ SCALE folded into q) + k_new/v_new
    norm_rope<<<dim3(S_LEN, NH + NKH), 128, 0, stream>>>(
        qkvb, fcos, fsin, qw, kw, knew, vnew);

    // 3) v transpose for PV MFMA operand layout
    transpose_v<<<dim3((NKH * HD) / 64, S_LEN / 32), 256, 0, stream>>>(qkvb, vT);

    // 4) causal GQA flash attention (bf16 out)
    attn_mfma<<<dim3(32, NH), 256, 0, stream>>>(qkvb, vT, attnb);

    // 5) output projection (fp32 out), 128x64 tiles -> 512 blocks
    gemm_n64<<<dim3(HID / 64, S_LEN / 128), 256, 0, stream>>>(
        attnb, hidb, out, S_LEN, HID, HID);
}

// Round 5
// 272.987 us; speedup vs baseline: 9.9175x; 1.0755x over previous
//
#include <hip/hip_runtime.h>
#include <hip/hip_bf16.h>
#include <math.h>

#define S_LEN 2048
#define HID 2048
#define NH 16
#define NKH 8
#define HD 128
#define QKV_N 4096
#define SCALE 0.08838834764831845f
#define EPS 1e-6f
#define LOG2E 1.4426950408889634f

typedef __hip_bfloat16 bf16;
typedef unsigned int u32;
typedef __bf16 bf16x8 __attribute__((ext_vector_type(8)));
typedef float f32x4 __attribute__((ext_vector_type(4)));

#define MFMA(a, b, c) __builtin_amdgcn_mfma_f32_16x16x32_bf16(a, b, c, 0, 0, 0)

static __device__ __forceinline__ bf16x8 ld_frag(const bf16* p) {
    return __builtin_bit_cast(bf16x8, *(const uint4*)p);
}

// async global->LDS, 16 B per lane. LDS dest = wave-uniform base + lane*16.
static __device__ __forceinline__ void gload_lds16(const void* g, void* l) {
    __builtin_amdgcn_global_load_lds(
        (const __attribute__((address_space(1))) u32*)g,
        (__attribute__((address_space(3))) u32*)l, 16, 0, 0);
}

// ---------------------------------------------------------------------------
// merged fp32 -> bf16: hidden | Wq | Wk | Wv | Wo in one launch.
// float4-unit thresholds: 1M | 2M | 2.5M | 3M | 4M. grid = 16384 x 256.
// ---------------------------------------------------------------------------
__global__ __launch_bounds__(256) void cvt5(
    const float* __restrict__ s0, const float* __restrict__ s1,
    const float* __restrict__ s2, const float* __restrict__ s3,
    const float* __restrict__ s4,
    bf16* __restrict__ d0, bf16* __restrict__ d1, bf16* __restrict__ d2,
    bf16* __restrict__ d3, bf16* __restrict__ d4)
{
    int i = blockIdx.x * 256 + threadIdx.x;
    const float* s; bf16* d; int off;
    if (i < (1 << 20))                   { s = s0; d = d0; off = 0; }
    else if (i < (2 << 20))              { s = s1; d = d1; off = 1 << 20; }
    else if (i < (2 << 20) + (1 << 19))  { s = s2; d = d2; off = 2 << 20; }
    else if (i < (3 << 20))              { s = s3; d = d3; off = (2 << 20) + (1 << 19); }
    else                                 { s = s4; d = d4; off = 3 << 20; }
    int j = i - off;
    float4 v = ((const float4*)s)[j];
    bf16* p = d + 4 * (size_t)j;
    p[0] = __float2bfloat16(v.x);
    p[1] = __float2bfloat16(v.y);
    p[2] = __float2bfloat16(v.z);
    p[3] = __float2bfloat16(v.w);
}

// ---------------------------------------------------------------------------
// QKV GEMM + fused epilogue. C = hidden * Wqkv^T, 128x128 tiles, BK=32,
// global_load_lds staging (m97 pattern). Wave w owns a 32x128 strip so each
// C-row is wave-local: RMSNorm = 8 in-lane squares + 4 shuffles; RoPE pair
// (d, d+64) = regs (j, j+4) of the SAME lane. n0-tile == one head.
//   q heads  (n0<2048):  norm(qw)+rope, *SCALE, -> qkvb
//   k heads  (<3072):    norm(kw)+rope -> qkvb; row 2047 -> knew (fp32)
//   v heads  (>=3072):   raw -> vT transposed (packed uint2); row 2047 -> vnew
// ---------------------------------------------------------------------------
__global__ __launch_bounds__(256) void gemm_qkv(
    const bf16* __restrict__ A, const bf16* __restrict__ B,
    bf16* __restrict__ qkvb, bf16* __restrict__ vT,
    const float* __restrict__ fcos, const float* __restrict__ fsin,
    const float* __restrict__ qw, const float* __restrict__ kw,
    float* __restrict__ knew, float* __restrict__ vnew)
{
    __shared__ bf16 As[128 * 32];
    __shared__ bf16 Bs[128 * 32];
    const int tid = threadIdx.x;
    const int n0 = blockIdx.x * 128, m0 = blockIdx.y * 128;
    const int w = tid >> 6, lane = tid & 63;
    const int l15 = lane & 15, quad = lane >> 4;

    f32x4 acc[2][8];
    #pragma unroll
    for (int i = 0; i < 2; ++i)
        #pragma unroll
        for (int j = 0; j < 8; ++j)
            acc[i][j] = f32x4{0.f, 0.f, 0.f, 0.f};

    const int grow = lane >> 2;
    const int gcol = ((lane & 3) ^ ((lane >> 3) & 3)) * 8;
    const int fcol = (quad ^ ((l15 >> 1) & 3)) * 8;

    for (int k0 = 0; k0 < HID; k0 += 32) {
        __syncthreads();
        #pragma unroll
        for (int j = 0; j < 2; ++j) {
            int c = 2 * w + j;
            int row = 16 * c + grow;
            gload_lds16(A + (size_t)(m0 + row) * HID + k0 + gcol, &As[c * 512]);
            gload_lds16(B + (size_t)(n0 + row) * HID + k0 + gcol, &Bs[c * 512]);
        }
        __syncthreads();

        bf16x8 av[2], bv[8];
        #pragma unroll
        for (int i = 0; i < 2; ++i)
            av[i] = ld_frag(&As[(w * 32 + i * 16 + l15) * 32 + fcol]);
        #pragma unroll
        for (int j = 0; j < 8; ++j)
            bv[j] = ld_frag(&Bs[(j * 16 + l15) * 32 + fcol]);
        #pragma unroll
        for (int i = 0; i < 2; ++i)
            #pragma unroll
            for (int j = 0; j < 8; ++j)
                acc[i][j] = MFMA(av[i], bv[j], acc[i][j]);
    }

    const int hblk = n0 >> 7;          // 0..15 q | 16..23 k | 24..31 v
    if (hblk < 24) {
        const float* wgt = (hblk < 16) ? qw : kw;
        float wv[8];
        #pragma unroll
        for (int j = 0; j < 8; ++j) wv[j] = wgt[j * 16 + l15];
        const size_t cb = (hblk < 16) ? (size_t)hblk * HD
                                      : (size_t)HID + (size_t)(hblk - 16) * HD;
        #pragma unroll
        for (int i = 0; i < 2; ++i)
            #pragma unroll
            for (int r = 0; r < 4; ++r) {
                int srow = m0 + w * 32 + i * 16 + quad * 4 + r;
                float ss = 0.f;
                #pragma unroll
                for (int j = 0; j < 8; ++j) ss += acc[i][j][r] * acc[i][j][r];
                ss += __shfl_xor(ss, 1);
                ss += __shfl_xor(ss, 2);
                ss += __shfl_xor(ss, 4);
                ss += __shfl_xor(ss, 8);
                float rr = rsqrtf(ss * (1.0f / 128.0f) + EPS);
                float x[8], res[8];
                #pragma unroll
                for (int j = 0; j < 8; ++j) x[j] = acc[i][j][r] * rr * wv[j];
                #pragma unroll
                for (int jj = 0; jj < 4; ++jj) {
                    float c = fcos[srow * 64 + jj * 16 + l15];
                    float s = fsin[srow * 64 + jj * 16 + l15];
                    res[jj]     = x[jj] * c - x[jj + 4] * s;
                    res[jj + 4] = x[jj] * s + x[jj + 4] * c;
                }
                if (hblk < 16) {
                    #pragma unroll
                    for (int j = 0; j < 8; ++j)
                        qkvb[(size_t)srow * QKV_N + cb + j * 16 + l15] =
                            __float2bfloat16(res[j] * SCALE);
                } else {
                    #pragma unroll
                    for (int j = 0; j < 8; ++j)
                        qkvb[(size_t)srow * QKV_N + cb + j * 16 + l15] =
                            __float2bfloat16(res[j]);
                    if (srow == S_LEN - 1) {
                        #pragma unroll
                        for (int j = 0; j < 8; ++j)
                            knew[(hblk - 16) * HD + j * 16 + l15] = res[j];
                    }
                }
            }
    } else {
        const int kh = hblk - 24;
        #pragma unroll
        for (int i = 0; i < 2; ++i)
            #pragma unroll
            for (int j = 0; j < 8; ++j) {
                int d = j * 16 + l15;
                int rowbase = m0 + w * 32 + i * 16 + quad * 4;
                union { uint2 u; bf16 hh[4]; } pk;
                #pragma unroll
                for (int r = 0; r < 4; ++r)
                    pk.hh[r] = __float2bfloat16(acc[i][j][r]);
                *(uint2*)&vT[(size_t)(kh * HD + d) * S_LEN + rowbase] = pk.u;
                if (rowbase == S_LEN - 4)
                    vnew[kh * HD + d] = acc[i][j][3];
            }
    }
}

// ---------------------------------------------------------------------------
// 128(M)x64(N)-tile GEMM, fp32 out — out-projection (512 blocks, 2+/CU).
// ---------------------------------------------------------------------------
__global__ __launch_bounds__(256, 3) void gemm_n64(
    const bf16* __restrict__ A, const bf16* __restrict__ B,
    float* __restrict__ C, int M, int N, int K)
{
    __shared__ bf16 As[128 * 32];
    __shared__ bf16 Bs[64 * 32];
    const int tid = threadIdx.x;
    const int n0 = blockIdx.x * 64, m0 = blockIdx.y * 128;
    const int w = tid >> 6, lane = tid & 63;
    const int l15 = lane & 15, quad = lane >> 4;

    f32x4 acc[2][4];
    #pragma unroll
    for (int i = 0; i < 2; ++i)
        #pragma unroll
        for (int j = 0; j < 4; ++j)
            acc[i][j] = f32x4{0.f, 0.f, 0.f, 0.f};

    const int grow = lane >> 2;
    const int gcol = ((lane & 3) ^ ((lane >> 3) & 3)) * 8;
    const int fcol = (quad ^ ((l15 >> 1) & 3)) * 8;

    for (int k0 = 0; k0 < K; k0 += 32) {
        __syncthreads();
        #pragma unroll
        for (int j = 0; j < 3; ++j) {
            int c = 3 * w + j;                 // 0..11: 8 A-chunks, 4 B-chunks
            if (c < 8) {
                int row = 16 * c + grow;
                gload_lds16(A + (size_t)(m0 + row) * K + k0 + gcol, &As[c * 512]);
            } else {
                int row = 16 * (c - 8) + grow;
                gload_lds16(B + (size_t)(n0 + row) * K + k0 + gcol, &Bs[(c - 8) * 512]);
            }
        }
        __syncthreads();

        bf16x8 av[2], bv[4];
        #pragma unroll
        for (int i = 0; i < 2; ++i)
            av[i] = ld_frag(&As[(w * 32 + i * 16 + l15) * 32 + fcol]);
        #pragma unroll
        for (int j = 0; j < 4; ++j)
            bv[j] = ld_frag(&Bs[(j * 16 + l15) * 32 + fcol]);
        #pragma unroll
        for (int i = 0; i < 2; ++i)
            #pragma unroll
            for (int j = 0; j < 4; ++j)
                acc[i][j] = MFMA(av[i], bv[j], acc[i][j]);
    }

    #pragma unroll
    for (int i = 0; i < 2; ++i)
        #pragma unroll
        for (int j = 0; j < 4; ++j)
            #pragma unroll
            for (int r = 0; r < 4; ++r)
                C[(size_t)(m0 + w * 32 + i * 16 + quad * 4 + r) * N +
                  n0 + j * 16 + l15] = acc[i][j][r];
}

// ---------------------------------------------------------------------------
// Flash attention v5: transposed-S, async dbuf, K-tile 32.
// LDS = 2*8K + 2*8K + 5K = 37 KB -> 3 blocks/CU (launch_bounds 256,3)
// = 12 waves/CU. grid (32,16), 4 waves x 16 q-rows (64-row Q tile).
// ---------------------------------------------------------------------------
__global__ __launch_bounds__(256, 3) void attn_mfma(
    const bf16* __restrict__ qkvb, const bf16* __restrict__ vT,
    bf16* __restrict__ outb)
{
    __shared__ bf16 Ks[2][32 * 128];
    __shared__ bf16 Vs[2][128 * 32];
    __shared__ bf16 Ps[4][16 * 40];

    const int x = blockIdx.x;
    const int h = blockIdx.y, kvh = h >> 1;
    int a = (x & 1) ? (31 - (x >> 1)) : (x >> 1);
    const int qb = (h < 8) ? a : 31 - a;       // heavy/light pairing across CUs
    const int tid = threadIdx.x, w = tid >> 6, lane = tid & 63;
    const int l15 = lane & 15, quad = lane >> 4;
    const int qw0 = qb * 64 + w * 16;          // this wave's 16 q-rows

    bf16x8 qf[4];
    #pragma unroll
    for (int dk = 0; dk < 4; ++dk)
        qf[dk] = ld_frag(qkvb + (size_t)(qw0 + l15) * QKV_N +
                         h * HD + dk * 32 + quad * 8);

    f32x4 o[8];
    #pragma unroll
    for (int dt = 0; dt < 8; ++dt) o[dt] = f32x4{0.f, 0.f, 0.f, 0.f};
    float m_st = -1e30f, l_st = 0.f;

    // waves 0,1 stage K (32x128); waves 2,3 stage V^T (128x32)
    auto stage = [&](int t, int nb) {
        const int kt0 = t * 32;
        if (w < 2) {
            #pragma unroll
            for (int c = 0; c < 4; ++c) {
                int chunk = w * 4 + c;                 // 0..7
                int row = 4 * chunk + (lane >> 4);
                int ls = (lane & 15) ^ (row & 15);
                gload_lds16(qkvb + (size_t)(kt0 + row) * QKV_N + HID +
                            kvh * HD + ls * 8,
                            &Ks[nb][chunk * 512]);
            }
        } else {
            #pragma unroll
            for (int c = 0; c < 4; ++c) {
                int chunk = (w - 2) * 4 + c;           // 0..7
                int row = 16 * chunk + (lane >> 2);
                int ls = (lane & 3) ^ ((lane >> 3) & 3);
                gload_lds16(vT + (size_t)(kvh * HD + row) * S_LEN + kt0 + ls * 8,
                            &Vs[nb][chunk * 512]);
            }
        }
    };

    stage(0, 0);
    const int tmax = 2 * qb + 1;
    for (int t = 0; t <= tmax; ++t) {
        const int pp = t & 1;
        const int kt0 = t * 32;
        __syncthreads();                  // drains stage(t)
        if (t < tmax) stage(t + 1, pp ^ 1);
        if (kt0 > qw0 + 15) continue;     // wave fully masked this tile

        // ---- S^T = K Q^T ----
        f32x4 sc[2];
        sc[0] = f32x4{0.f, 0.f, 0.f, 0.f};
        sc[1] = f32x4{0.f, 0.f, 0.f, 0.f};
        #pragma unroll
        for (int dk = 0; dk < 4; ++dk)
            #pragma unroll
            for (int mt = 0; mt < 2; ++mt) {
                bf16x8 kf = ld_frag(&Ks[pp][(mt * 16 + l15) * 128 +
                                            (((dk * 4 + quad) ^ l15) & 15) * 8]);
                sc[mt] = MFMA(kf, qf[dk], sc[mt]);
            }

        // ---- causal mask (near-diagonal tiles only) ----
        if (kt0 + 31 > qw0) {
            #pragma unroll
            for (int mt = 0; mt < 2; ++mt)
                #pragma unroll
                for (int r = 0; r < 4; ++r) {
                    int kg = kt0 + mt * 16 + quad * 4 + r;
                    if (kg > qw0 + l15) sc[mt][r] = -1e30f;
                }
        }

        // ---- online softmax (8 in-lane regs + 2 shuffles) ----
        float mx = -1e30f;
        #pragma unroll
        for (int mt = 0; mt < 2; ++mt)
            #pragma unroll
            for (int r = 0; r < 4; ++r) mx = fmaxf(mx, sc[mt][r]);
        mx = fmaxf(mx, __shfl_xor(mx, 16, 64));
        mx = fmaxf(mx, __shfl_xor(mx, 32, 64));
        float mnew = fmaxf(m_st, mx);
        float al = exp2f((m_st - mnew) * LOG2E);
        m_st = mnew;
        float rs = 0.f;
        #pragma unroll
        for (int mt = 0; mt < 2; ++mt) {
            union { uint2 u; bf16 hh[4]; } pk;
            #pragma unroll
            for (int r = 0; r < 4; ++r) {
                float p = exp2f((sc[mt][r] - mnew) * LOG2E);
                pk.hh[r] = __float2bfloat16(p);
                rs += p;
            }
            *(uint2*)&Ps[w][l15 * 40 + mt * 16 + quad * 4] = pk.u;
        }
        rs += __shfl_xor(rs, 16, 64);
        rs += __shfl_xor(rs, 32, 64);
        l_st = l_st * al + rs;

        #pragma unroll
        for (int dt = 0; dt < 8; ++dt)
            #pragma unroll
            for (int r = 0; r < 4; ++r) o[dt][r] *= al;

        // ---- O^T += V^T P^T ----
        bf16x8 pf = ld_frag(&Ps[w][l15 * 40 + quad * 8]);
        #pragma unroll
        for (int dt = 0; dt < 8; ++dt) {
            bf16x8 vf = ld_frag(&Vs[pp][(dt * 16 + l15) * 32 +
                                        ((quad ^ ((l15 >> 1) & 3)) * 8)]);
            o[dt] = MFMA(vf, pf, o[dt]);
        }
    }

    float inv = 1.0f / l_st;
    int qg = qw0 + l15;
    #pragma unroll
    for (int dt = 0; dt < 8; ++dt) {
        union { uint2 u; bf16 hh[4]; } pk;
        #pragma unroll
        for (int r = 0; r < 4; ++r)
            pk.hh[r] = __float2bfloat16(o[dt][r] * inv);
        *(uint2*)&outb[(size_t)qg * HID + h * HD + dt * 16 + quad * 4] = pk.u;
    }
}

// ---------------------------------------------------------------------------
extern "C" void kernel_launch(void* const* d_in, const int* in_sizes, int n_in,
                              void* d_out, int out_size, void* d_ws, size_t ws_size,
                              hipStream_t stream) {
    const float* hidden = (const float*)d_in[0];
    const float* fcos   = (const float*)d_in[1];
    const float* fsin   = (const float*)d_in[2];
    // d_in[3] atten_mask: causal, applied analytically
    const float* Wq = (const float*)d_in[4];
    const float* Wk = (const float*)d_in[5];
    const float* Wv = (const float*)d_in[6];
    const float* Wo = (const float*)d_in[7];
    const float* qw = (const float*)d_in[8];
    const float* kw = (const float*)d_in[9];
    float* out = (float*)d_out;

    bf16* qkvb  = (bf16*)d_ws;                          // 2048 x 4096 (q|k normed; v region unused)
    bf16* vT    = qkvb + (size_t)S_LEN * QKV_N;         // 1024 x 2048 (V^T)
    bf16* attnb = vT + (size_t)NKH * HD * S_LEN;        // 2048 x 2048
    bf16* wqkvb = attnb + (size_t)S_LEN * HID;          // 4096 x 2048
    bf16* hidb  = wqkvb + (size_t)QKV_N * HID;          // 2048 x 2048
    bf16* wob   = hidb + (size_t)S_LEN * HID;           // 2048 x 2048

    float* knew = out + (size_t)S_LEN * HID;
    float* vnew = knew + NKH * HD;

    // 0) all conversions in one launch (4M float4 units)
    cvt5<<<16384, 256, 0, stream>>>(
        hidden, Wq, Wk, Wv, Wo,
        hidb, wqkvb, wqkvb + (size_t)HID * HID,
        wqkvb + (size_t)(HID + NKH * HD) * HID, wob);

    // 1) QKV projection + fused RMSNorm/RoPE/SCALE/V-transpose/knew/vnew
    gemm_qkv<<<dim3(QKV_N / 128, S_LEN / 128), 256, 0, stream>>>(
        hidb, wqkvb, qkvb, vT, fcos, fsin, qw, kw, knew, vnew);

    // 2) causal GQA flash attention (bf16 out)
    attn_mfma<<<dim3(32, NH), 256, 0, stream>>>(qkvb, vT, attnb);

    // 3) output projection (fp32 out), 128x64 tiles -> 512 blocks
    gemm_n64<<<dim3(HID / 64, S_LEN / 128), 256, 0, stream>>>(
        attnb, wob, out, S_LEN, HID, HID);
}

// Round 6
// 265.292 us; speedup vs baseline: 10.2052x; 1.0290x over previous
//
#include <hip/hip_runtime.h>
#include <hip/hip_bf16.h>
#include <math.h>

#define S_LEN 2048
#define HID 2048
#define NH 16
#define NKH 8
#define HD 128
#define QKV_N 4096
#define SCALE 0.08838834764831845f
#define EPS 1e-6f
#define LOG2E 1.4426950408889634f
#define QSCALE (SCALE * LOG2E)     // fold log2(e) into q so p = exp2(score)

typedef __hip_bfloat16 bf16;
typedef unsigned int u32;
typedef __bf16 bf16x8 __attribute__((ext_vector_type(8)));
typedef float f32x4 __attribute__((ext_vector_type(4)));

#define MFMA(a, b, c) __builtin_amdgcn_mfma_f32_16x16x32_bf16(a, b, c, 0, 0, 0)

static __device__ __forceinline__ bf16x8 ld_frag(const bf16* p) {
    return __builtin_bit_cast(bf16x8, *(const uint4*)p);
}

// async global->LDS, 16 B per lane. LDS dest = wave-uniform base + lane*16.
static __device__ __forceinline__ void gload_lds16(const void* g, void* l) {
    __builtin_amdgcn_global_load_lds(
        (const __attribute__((address_space(1))) u32*)g,
        (__attribute__((address_space(3))) u32*)l, 16, 0, 0);
}

// ---------------------------------------------------------------------------
// merged fp32 -> bf16: hidden | Wq | Wk | Wv | Wo in one launch.
// float4-unit thresholds: 1M | 2M | 2.5M | 3M | 4M. grid = 16384 x 256.
// ---------------------------------------------------------------------------
__global__ __launch_bounds__(256) void cvt5(
    const float* __restrict__ s0, const float* __restrict__ s1,
    const float* __restrict__ s2, const float* __restrict__ s3,
    const float* __restrict__ s4,
    bf16* __restrict__ d0, bf16* __restrict__ d1, bf16* __restrict__ d2,
    bf16* __restrict__ d3, bf16* __restrict__ d4)
{
    int i = blockIdx.x * 256 + threadIdx.x;
    const float* s; bf16* d; int off;
    if (i < (1 << 20))                   { s = s0; d = d0; off = 0; }
    else if (i < (2 << 20))              { s = s1; d = d1; off = 1 << 20; }
    else if (i < (2 << 20) + (1 << 19))  { s = s2; d = d2; off = 2 << 20; }
    else if (i < (3 << 20))              { s = s3; d = d3; off = (2 << 20) + (1 << 19); }
    else                                 { s = s4; d = d4; off = 3 << 20; }
    int j = i - off;
    float4 v = ((const float4*)s)[j];
    bf16* p = d + 4 * (size_t)j;
    p[0] = __float2bfloat16(v.x);
    p[1] = __float2bfloat16(v.y);
    p[2] = __float2bfloat16(v.z);
    p[3] = __float2bfloat16(v.w);
}

// ---------------------------------------------------------------------------
// QKV GEMM + fused epilogue. 64(M)x128(N) tiles, BK=32 -> grid (32,32) =
// 1024 blocks = 4 blocks/CU. N-tile == one head, so RMSNorm/RoPE stay
// epilogue-local: each C-row is wave-local (sumsq = 8 in-lane + 4 shuffles),
// RoPE pair (d, d+64) = regs (j, j+4) of the same lane.
//   q heads: norm(qw)+rope, * SCALE*LOG2E -> qkvb
//   k heads: norm(kw)+rope -> qkvb; row 2047 -> knew (fp32)
//   v heads: raw -> vT transposed (packed uint2); row 2047 -> vnew
// ---------------------------------------------------------------------------
__global__ __launch_bounds__(256, 4) void gemm_qkv(
    const bf16* __restrict__ A, const bf16* __restrict__ B,
    bf16* __restrict__ qkvb, bf16* __restrict__ vT,
    const float* __restrict__ fcos, const float* __restrict__ fsin,
    const float* __restrict__ qw, const float* __restrict__ kw,
    float* __restrict__ knew, float* __restrict__ vnew)
{
    __shared__ bf16 As[64 * 32];
    __shared__ bf16 Bs[128 * 32];
    const int tid = threadIdx.x;
    const int n0 = blockIdx.x * 128, m0 = blockIdx.y * 64;
    const int w = tid >> 6, lane = tid & 63;
    const int l15 = lane & 15, quad = lane >> 4;

    f32x4 acc[8];
    #pragma unroll
    for (int j = 0; j < 8; ++j) acc[j] = f32x4{0.f, 0.f, 0.f, 0.f};

    const int grow = lane >> 2;
    const int gcol = ((lane & 3) ^ ((lane >> 3) & 3)) * 8;
    const int fcol = (quad ^ ((l15 >> 1) & 3)) * 8;

    for (int k0 = 0; k0 < HID; k0 += 32) {
        __syncthreads();
        #pragma unroll
        for (int j = 0; j < 3; ++j) {
            int c = 3 * w + j;                 // 0..11: 4 A-chunks, 8 B-chunks
            if (c < 4) {
                int row = 16 * c + grow;
                gload_lds16(A + (size_t)(m0 + row) * HID + k0 + gcol, &As[c * 512]);
            } else {
                int row = 16 * (c - 4) + grow;
                gload_lds16(B + (size_t)(n0 + row) * HID + k0 + gcol, &Bs[(c - 4) * 512]);
            }
        }
        __syncthreads();

        bf16x8 av = ld_frag(&As[(w * 16 + l15) * 32 + fcol]);
        #pragma unroll
        for (int j = 0; j < 8; ++j) {
            bf16x8 bv = ld_frag(&Bs[(j * 16 + l15) * 32 + fcol]);
            acc[j] = MFMA(av, bv, acc[j]);
        }
    }

    const int hblk = n0 >> 7;          // 0..15 q | 16..23 k | 24..31 v
    if (hblk < 24) {
        const float* wgt = (hblk < 16) ? qw : kw;
        float wv[8];
        #pragma unroll
        for (int j = 0; j < 8; ++j) wv[j] = wgt[j * 16 + l15];
        const size_t cb = (hblk < 16) ? (size_t)hblk * HD
                                      : (size_t)HID + (size_t)(hblk - 16) * HD;
        #pragma unroll
        for (int r = 0; r < 4; ++r) {
            int srow = m0 + w * 16 + quad * 4 + r;
            float ss = 0.f;
            #pragma unroll
            for (int j = 0; j < 8; ++j) ss += acc[j][r] * acc[j][r];
            ss += __shfl_xor(ss, 1);
            ss += __shfl_xor(ss, 2);
            ss += __shfl_xor(ss, 4);
            ss += __shfl_xor(ss, 8);
            float rr = rsqrtf(ss * (1.0f / 128.0f) + EPS);
            float x[8], res[8];
            #pragma unroll
            for (int j = 0; j < 8; ++j) x[j] = acc[j][r] * rr * wv[j];
            #pragma unroll
            for (int jj = 0; jj < 4; ++jj) {
                float c = fcos[srow * 64 + jj * 16 + l15];
                float s = fsin[srow * 64 + jj * 16 + l15];
                res[jj]     = x[jj] * c - x[jj + 4] * s;
                res[jj + 4] = x[jj] * s + x[jj + 4] * c;
            }
            if (hblk < 16) {
                #pragma unroll
                for (int j = 0; j < 8; ++j)
                    qkvb[(size_t)srow * QKV_N + cb + j * 16 + l15] =
                        __float2bfloat16(res[j] * QSCALE);
            } else {
                #pragma unroll
                for (int j = 0; j < 8; ++j)
                    qkvb[(size_t)srow * QKV_N + cb + j * 16 + l15] =
                        __float2bfloat16(res[j]);
                if (srow == S_LEN - 1) {
                    #pragma unroll
                    for (int j = 0; j < 8; ++j)
                        knew[(hblk - 16) * HD + j * 16 + l15] = res[j];
                }
            }
        }
    } else {
        const int kh = hblk - 24;
        int rowbase = m0 + w * 16 + quad * 4;
        #pragma unroll
        for (int j = 0; j < 8; ++j) {
            int d = j * 16 + l15;
            union { uint2 u; bf16 hh[4]; } pk;
            #pragma unroll
            for (int r = 0; r < 4; ++r)
                pk.hh[r] = __float2bfloat16(acc[j][r]);
            *(uint2*)&vT[(size_t)(kh * HD + d) * S_LEN + rowbase] = pk.u;
            if (rowbase == S_LEN - 4)
                vnew[kh * HD + d] = acc[j][3];
        }
    }
}

// ---------------------------------------------------------------------------
// 128(M)x64(N)-tile GEMM, fp32 out — out-projection (512 blocks, 2+/CU).
// ---------------------------------------------------------------------------
__global__ __launch_bounds__(256, 3) void gemm_n64(
    const bf16* __restrict__ A, const bf16* __restrict__ B,
    float* __restrict__ C, int M, int N, int K)
{
    __shared__ bf16 As[128 * 32];
    __shared__ bf16 Bs[64 * 32];
    const int tid = threadIdx.x;
    const int n0 = blockIdx.x * 64, m0 = blockIdx.y * 128;
    const int w = tid >> 6, lane = tid & 63;
    const int l15 = lane & 15, quad = lane >> 4;

    f32x4 acc[2][4];
    #pragma unroll
    for (int i = 0; i < 2; ++i)
        #pragma unroll
        for (int j = 0; j < 4; ++j)
            acc[i][j] = f32x4{0.f, 0.f, 0.f, 0.f};

    const int grow = lane >> 2;
    const int gcol = ((lane & 3) ^ ((lane >> 3) & 3)) * 8;
    const int fcol = (quad ^ ((l15 >> 1) & 3)) * 8;

    for (int k0 = 0; k0 < K; k0 += 32) {
        __syncthreads();
        #pragma unroll
        for (int j = 0; j < 3; ++j) {
            int c = 3 * w + j;                 // 0..11: 8 A-chunks, 4 B-chunks
            if (c < 8) {
                int row = 16 * c + grow;
                gload_lds16(A + (size_t)(m0 + row) * K + k0 + gcol, &As[c * 512]);
            } else {
                int row = 16 * (c - 8) + grow;
                gload_lds16(B + (size_t)(n0 + row) * K + k0 + gcol, &Bs[(c - 8) * 512]);
            }
        }
        __syncthreads();

        bf16x8 av[2], bv[4];
        #pragma unroll
        for (int i = 0; i < 2; ++i)
            av[i] = ld_frag(&As[(w * 32 + i * 16 + l15) * 32 + fcol]);
        #pragma unroll
        for (int j = 0; j < 4; ++j)
            bv[j] = ld_frag(&Bs[(j * 16 + l15) * 32 + fcol]);
        #pragma unroll
        for (int i = 0; i < 2; ++i)
            #pragma unroll
            for (int j = 0; j < 4; ++j)
                acc[i][j] = MFMA(av[i], bv[j], acc[i][j]);
    }

    #pragma unroll
    for (int i = 0; i < 2; ++i)
        #pragma unroll
        for (int j = 0; j < 4; ++j)
            #pragma unroll
            for (int r = 0; r < 4; ++r)
                C[(size_t)(m0 + w * 32 + i * 16 + quad * 4 + r) * N +
                  n0 + j * 16 + l15] = acc[i][j][r];
}

// ---------------------------------------------------------------------------
// Flash attention v6: fixed-reference softmax (no online max — post-RMSNorm
// scores are bounded: |s| <= 11.4, exp(11.4)*2048 ~ 2e8 << fp32 max), so
// p = exp2(score_log2e) directly, l accumulated lane-partially and reduced
// ONCE in the epilogue. Transposed-S scheme, async dbuf, K-tile 32.
// grid (32,16), 4 waves x 16 q-rows. LDS 37.8 KB.
// ---------------------------------------------------------------------------
__global__ __launch_bounds__(256, 3) void attn_mfma(
    const bf16* __restrict__ qkvb, const bf16* __restrict__ vT,
    bf16* __restrict__ outb)
{
    __shared__ bf16 Ks[2][32 * 128];
    __shared__ bf16 Vs[2][128 * 32];
    __shared__ bf16 Ps[4][16 * 40];

    const int x = blockIdx.x;
    const int h = blockIdx.y, kvh = h >> 1;
    int a = (x & 1) ? (31 - (x >> 1)) : (x >> 1);
    const int qb = (h < 8) ? a : 31 - a;       // heavy/light pairing across CUs
    const int tid = threadIdx.x, w = tid >> 6, lane = tid & 63;
    const int l15 = lane & 15, quad = lane >> 4;
    const int qw0 = qb * 64 + w * 16;          // this wave's 16 q-rows

    bf16x8 qf[4];
    #pragma unroll
    for (int dk = 0; dk < 4; ++dk)
        qf[dk] = ld_frag(qkvb + (size_t)(qw0 + l15) * QKV_N +
                         h * HD + dk * 32 + quad * 8);

    f32x4 o[8];
    #pragma unroll
    for (int dt = 0; dt < 8; ++dt) o[dt] = f32x4{0.f, 0.f, 0.f, 0.f};
    float l_st = 0.f;                          // lane-partial sum of P

    // waves 0,1 stage K (32x128); waves 2,3 stage V^T (128x32)
    auto stage = [&](int t, int nb) {
        const int kt0 = t * 32;
        if (w < 2) {
            #pragma unroll
            for (int c = 0; c < 4; ++c) {
                int chunk = w * 4 + c;                 // 0..7
                int row = 4 * chunk + (lane >> 4);
                int ls = (lane & 15) ^ (row & 15);
                gload_lds16(qkvb + (size_t)(kt0 + row) * QKV_N + HID +
                            kvh * HD + ls * 8,
                            &Ks[nb][chunk * 512]);
            }
        } else {
            #pragma unroll
            for (int c = 0; c < 4; ++c) {
                int chunk = (w - 2) * 4 + c;           // 0..7
                int row = 16 * chunk + (lane >> 2);
                int ls = (lane & 3) ^ ((lane >> 3) & 3);
                gload_lds16(vT + (size_t)(kvh * HD + row) * S_LEN + kt0 + ls * 8,
                            &Vs[nb][chunk * 512]);
            }
        }
    };

    stage(0, 0);
    const int tmax = 2 * qb + 1;
    for (int t = 0; t <= tmax; ++t) {
        const int pp = t & 1;
        const int kt0 = t * 32;
        __syncthreads();                  // drains stage(t)
        if (t < tmax) stage(t + 1, pp ^ 1);
        if (kt0 > qw0 + 15) continue;     // wave fully masked this tile

        // ---- S^T = K Q^T  (scores pre-multiplied by log2e via QSCALE) ----
        f32x4 sc[2];
        sc[0] = f32x4{0.f, 0.f, 0.f, 0.f};
        sc[1] = f32x4{0.f, 0.f, 0.f, 0.f};
        #pragma unroll
        for (int dk = 0; dk < 4; ++dk)
            #pragma unroll
            for (int mt = 0; mt < 2; ++mt) {
                bf16x8 kf = ld_frag(&Ks[pp][(mt * 16 + l15) * 128 +
                                            (((dk * 4 + quad) ^ l15) & 15) * 8]);
                sc[mt] = MFMA(kf, qf[dk], sc[mt]);
            }

        // ---- causal mask (near-diagonal tiles only) ----
        if (kt0 + 31 > qw0) {
            #pragma unroll
            for (int mt = 0; mt < 2; ++mt)
                #pragma unroll
                for (int r = 0; r < 4; ++r) {
                    int kg = kt0 + mt * 16 + quad * 4 + r;
                    if (kg > qw0 + l15) sc[mt][r] = -1e30f;
                }
        }

        // ---- P = exp2(sc), lane-partial l, pack -> Ps ----
        #pragma unroll
        for (int mt = 0; mt < 2; ++mt) {
            union { uint2 u; bf16 hh[4]; } pk;
            #pragma unroll
            for (int r = 0; r < 4; ++r) {
                float p = exp2f(sc[mt][r]);
                pk.hh[r] = __float2bfloat16(p);
                l_st += p;
            }
            *(uint2*)&Ps[w][l15 * 40 + mt * 16 + quad * 4] = pk.u;
        }

        // ---- O^T += V^T P^T ----
        bf16x8 pf = ld_frag(&Ps[w][l15 * 40 + quad * 8]);
        #pragma unroll
        for (int dt = 0; dt < 8; ++dt) {
            bf16x8 vf = ld_frag(&Vs[pp][(dt * 16 + l15) * 32 +
                                        ((quad ^ ((l15 >> 1) & 3)) * 8)]);
            o[dt] = MFMA(vf, pf, o[dt]);
        }
    }

    // ---- epilogue: reduce l across quads once, divide, store ----
    l_st += __shfl_xor(l_st, 16, 64);
    l_st += __shfl_xor(l_st, 32, 64);
    float inv = 1.0f / l_st;
    int qg = qw0 + l15;
    #pragma unroll
    for (int dt = 0; dt < 8; ++dt) {
        union { uint2 u; bf16 hh[4]; } pk;
        #pragma unroll
        for (int r = 0; r < 4; ++r)
            pk.hh[r] = __float2bfloat16(o[dt][r] * inv);
        *(uint2*)&outb[(size_t)qg * HID + h * HD + dt * 16 + quad * 4] = pk.u;
    }
}

// ---------------------------------------------------------------------------
extern "C" void kernel_launch(void* const* d_in, const int* in_sizes, int n_in,
                              void* d_out, int out_size, void* d_ws, size_t ws_size,
                              hipStream_t stream) {
    const float* hidden = (const float*)d_in[0];
    const float* fcos   = (const float*)d_in[1];
    const float* fsin   = (const float*)d_in[2];
    // d_in[3] atten_mask: causal, applied analytically
    const float* Wq = (const float*)d_in[4];
    const float* Wk = (const float*)d_in[5];
    const float* Wv = (const float*)d_in[6];
    const float* Wo = (const float*)d_in[7];
    const float* qw = (const float*)d_in[8];
    const float* kw = (const float*)d_in[9];
    float* out = (float*)d_out;

    bf16* qkvb  = (bf16*)d_ws;                          // 2048 x 4096 (q|k normed)
    bf16* vT    = qkvb + (size_t)S_LEN * QKV_N;         // 1024 x 2048 (V^T)
    bf16* attnb = vT + (size_t)NKH * HD * S_LEN;        // 2048 x 2048
    bf16* wqkvb = attnb + (size_t)S_LEN * HID;          // 4096 x 2048
    bf16* hidb  = wqkvb + (size_t)QKV_N * HID;          // 2048 x 2048
    bf16* wob   = hidb + (size_t)S_LEN * HID;           // 2048 x 2048

    float* knew = out + (size_t)S_LEN * HID;
    float* vnew = knew + NKH * HD;

    // 0) all conversions in one launch (4M float4 units)
    cvt5<<<16384, 256, 0, stream>>>(
        hidden, Wq, Wk, Wv, Wo,
        hidb, wqkvb, wqkvb + (size_t)HID * HID,
        wqkvb + (size_t)(HID + NKH * HD) * HID, wob);

    // 1) QKV projection + fused RMSNorm/RoPE/QSCALE/V-transpose/knew/vnew
    //    64x128 tiles -> 1024 blocks (4/CU)
    gemm_qkv<<<dim3(QKV_N / 128, S_LEN / 64), 256, 0, stream>>>(
        hidb, wqkvb, qkvb, vT, fcos, fsin, qw, kw, knew, vnew);

    // 2) causal GQA flash attention (bf16 out), fixed-ref softmax
    attn_mfma<<<dim3(32, NH), 256, 0, stream>>>(qkvb, vT, attnb);

    // 3) output projection (fp32 out), 128x64 tiles -> 512 blocks
    gemm_n64<<<dim3(HID / 64, S_LEN / 128), 256, 0, stream>>>(
        attnb, wob, out, S_LEN, HID, HID);
}

// Round 7
// 240.851 us; speedup vs baseline: 11.2408x; 1.1015x over previous
//
#include <hip/hip_runtime.h>
#include <hip/hip_bf16.h>
#include <math.h>

#define S_LEN 2048
#define HID 2048
#define NH 16
#define NKH 8
#define HD 128
#define QKV_N 4096
#define SCALE 0.08838834764831845f
#define EPS 1e-6f
#define LOG2E 1.4426950408889634f
#define QSCALE (SCALE * LOG2E)     // fold log2(e) into q so p = exp2(score)

typedef __hip_bfloat16 bf16;
typedef unsigned int u32;
typedef __bf16 bf16x8 __attribute__((ext_vector_type(8)));
typedef float f32x4 __attribute__((ext_vector_type(4)));

#define MFMA(a, b, c) __builtin_amdgcn_mfma_f32_16x16x32_bf16(a, b, c, 0, 0, 0)

static __device__ __forceinline__ bf16x8 ld_frag(const bf16* p) {
    return __builtin_bit_cast(bf16x8, *(const uint4*)p);
}

// async global->LDS, 16 B per lane. LDS dest = wave-uniform base + lane*16.
static __device__ __forceinline__ void gload_lds16(const void* g, void* l) {
    __builtin_amdgcn_global_load_lds(
        (const __attribute__((address_space(1))) u32*)g,
        (__attribute__((address_space(3))) u32*)l, 16, 0, 0);
}

// ---------------------------------------------------------------------------
// merged fp32 -> bf16: hidden | Wq | Wk | Wv | Wo in one launch.
// float4-unit thresholds: 1M | 2M | 2.5M | 3M | 4M. grid = 16384 x 256.
// ---------------------------------------------------------------------------
__global__ __launch_bounds__(256) void cvt5(
    const float* __restrict__ s0, const float* __restrict__ s1,
    const float* __restrict__ s2, const float* __restrict__ s3,
    const float* __restrict__ s4,
    bf16* __restrict__ d0, bf16* __restrict__ d1, bf16* __restrict__ d2,
    bf16* __restrict__ d3, bf16* __restrict__ d4)
{
    int i = blockIdx.x * 256 + threadIdx.x;
    const float* s; bf16* d; int off;
    if (i < (1 << 20))                   { s = s0; d = d0; off = 0; }
    else if (i < (2 << 20))              { s = s1; d = d1; off = 1 << 20; }
    else if (i < (2 << 20) + (1 << 19))  { s = s2; d = d2; off = 2 << 20; }
    else if (i < (3 << 20))              { s = s3; d = d3; off = (2 << 20) + (1 << 19); }
    else                                 { s = s4; d = d4; off = 3 << 20; }
    int j = i - off;
    float4 v = ((const float4*)s)[j];
    bf16* p = d + 4 * (size_t)j;
    p[0] = __float2bfloat16(v.x);
    p[1] = __float2bfloat16(v.y);
    p[2] = __float2bfloat16(v.z);
    p[3] = __float2bfloat16(v.w);
}

// ---------------------------------------------------------------------------
// QKV GEMM + fused epilogue. 128x128 tiles (LDS-lean: 8 reads per 16 MFMA
// per wave per BK32) with BK=64 (half the barriers; 32 KB single buffer).
// LDS rows are 64 k-elems of 8 slots x 8; phys slot = logical ^ (row & 7).
// Wave w owns a 32(M)x128(N) strip -> epilogue rows wave-local:
//   q heads: RMSNorm(qw)+RoPE, * SCALE*LOG2E -> qkvb
//   k heads: RMSNorm(kw)+RoPE -> qkvb; row 2047 -> knew (fp32)
//   v heads: raw -> vT transposed (packed uint2); row 2047 -> vnew
// ---------------------------------------------------------------------------
__global__ __launch_bounds__(256, 2) void gemm_qkv(
    const bf16* __restrict__ A, const bf16* __restrict__ B,
    bf16* __restrict__ qkvb, bf16* __restrict__ vT,
    const float* __restrict__ fcos, const float* __restrict__ fsin,
    const float* __restrict__ qw, const float* __restrict__ kw,
    float* __restrict__ knew, float* __restrict__ vnew)
{
    __shared__ bf16 As[128 * 64];
    __shared__ bf16 Bs[128 * 64];
    const int tid = threadIdx.x;
    const int n0 = blockIdx.x * 128, m0 = blockIdx.y * 128;
    const int w = tid >> 6, lane = tid & 63;
    const int l15 = lane & 15, quad = lane >> 4;

    f32x4 acc[2][8];
    #pragma unroll
    for (int i = 0; i < 2; ++i)
        #pragma unroll
        for (int j = 0; j < 8; ++j)
            acc[i][j] = f32x4{0.f, 0.f, 0.f, 0.f};

    // staging: chunk = 8 rows x 64 k; lane -> row (lane>>3), phys slot lane&7
    const int srow8 = lane >> 3;
    const int sls = ((lane & 7) ^ srow8) * 8;   // logical k-slot fetched

    for (int k0 = 0; k0 < HID; k0 += 64) {
        __syncthreads();
        #pragma unroll
        for (int j = 0; j < 8; ++j) {
            int c = 8 * w + j;                 // 0..31: 16 A-chunks, 16 B-chunks
            if (c < 16) {
                int row = c * 8 + srow8;
                gload_lds16(A + (size_t)(m0 + row) * HID + k0 + sls, &As[c * 512]);
            } else {
                int row = (c - 16) * 8 + srow8;
                gload_lds16(B + (size_t)(n0 + row) * HID + k0 + sls, &Bs[(c - 16) * 512]);
            }
        }
        __syncthreads();

        #pragma unroll
        for (int kc = 0; kc < 2; ++kc) {
            const int ph = ((kc * 4 + quad) ^ (l15 & 7)) * 8;
            bf16x8 av[2], bv[8];
            av[0] = ld_frag(&As[(w * 32 + l15) * 64 + ph]);
            av[1] = ld_frag(&As[(w * 32 + 16 + l15) * 64 + ph]);
            #pragma unroll
            for (int j = 0; j < 8; ++j)
                bv[j] = ld_frag(&Bs[(j * 16 + l15) * 64 + ph]);
            #pragma unroll
            for (int i = 0; i < 2; ++i)
                #pragma unroll
                for (int j = 0; j < 8; ++j)
                    acc[i][j] = MFMA(av[i], bv[j], acc[i][j]);
        }
    }

    const int hblk = n0 >> 7;          // 0..15 q | 16..23 k | 24..31 v
    if (hblk < 24) {
        const float* wgt = (hblk < 16) ? qw : kw;
        float wv[8];
        #pragma unroll
        for (int j = 0; j < 8; ++j) wv[j] = wgt[j * 16 + l15];
        const size_t cb = (hblk < 16) ? (size_t)hblk * HD
                                      : (size_t)HID + (size_t)(hblk - 16) * HD;
        #pragma unroll
        for (int i = 0; i < 2; ++i)
            #pragma unroll
            for (int r = 0; r < 4; ++r) {
                int srow = m0 + w * 32 + i * 16 + quad * 4 + r;
                float ss = 0.f;
                #pragma unroll
                for (int j = 0; j < 8; ++j) ss += acc[i][j][r] * acc[i][j][r];
                ss += __shfl_xor(ss, 1);
                ss += __shfl_xor(ss, 2);
                ss += __shfl_xor(ss, 4);
                ss += __shfl_xor(ss, 8);
                float rr = rsqrtf(ss * (1.0f / 128.0f) + EPS);
                float x[8], res[8];
                #pragma unroll
                for (int j = 0; j < 8; ++j) x[j] = acc[i][j][r] * rr * wv[j];
                #pragma unroll
                for (int jj = 0; jj < 4; ++jj) {
                    float c = fcos[srow * 64 + jj * 16 + l15];
                    float s = fsin[srow * 64 + jj * 16 + l15];
                    res[jj]     = x[jj] * c - x[jj + 4] * s;
                    res[jj + 4] = x[jj] * s + x[jj + 4] * c;
                }
                if (hblk < 16) {
                    #pragma unroll
                    for (int j = 0; j < 8; ++j)
                        qkvb[(size_t)srow * QKV_N + cb + j * 16 + l15] =
                            __float2bfloat16(res[j] * QSCALE);
                } else {
                    #pragma unroll
                    for (int j = 0; j < 8; ++j)
                        qkvb[(size_t)srow * QKV_N + cb + j * 16 + l15] =
                            __float2bfloat16(res[j]);
                    if (srow == S_LEN - 1) {
                        #pragma unroll
                        for (int j = 0; j < 8; ++j)
                            knew[(hblk - 16) * HD + j * 16 + l15] = res[j];
                    }
                }
            }
    } else {
        const int kh = hblk - 24;
        #pragma unroll
        for (int i = 0; i < 2; ++i) {
            int rowbase = m0 + w * 32 + i * 16 + quad * 4;
            #pragma unroll
            for (int j = 0; j < 8; ++j) {
                int d = j * 16 + l15;
                union { uint2 u; bf16 hh[4]; } pk;
                #pragma unroll
                for (int r = 0; r < 4; ++r)
                    pk.hh[r] = __float2bfloat16(acc[i][j][r]);
                *(uint2*)&vT[(size_t)(kh * HD + d) * S_LEN + rowbase] = pk.u;
                if (rowbase == S_LEN - 4)
                    vnew[kh * HD + d] = acc[i][j][3];
            }
        }
    }
}

// ---------------------------------------------------------------------------
// 128(M)x64(N)-tile GEMM, BK=64, fp32 out — out-projection (512 blocks).
// LDS 24 KB; same 64-elem-row swizzled layout as gemm_qkv.
// ---------------------------------------------------------------------------
__global__ __launch_bounds__(256, 2) void gemm_n64(
    const bf16* __restrict__ A, const bf16* __restrict__ B,
    float* __restrict__ C, int M, int N, int K)
{
    __shared__ bf16 As[128 * 64];
    __shared__ bf16 Bs[64 * 64];
    const int tid = threadIdx.x;
    const int n0 = blockIdx.x * 64, m0 = blockIdx.y * 128;
    const int w = tid >> 6, lane = tid & 63;
    const int l15 = lane & 15, quad = lane >> 4;

    f32x4 acc[2][4];
    #pragma unroll
    for (int i = 0; i < 2; ++i)
        #pragma unroll
        for (int j = 0; j < 4; ++j)
            acc[i][j] = f32x4{0.f, 0.f, 0.f, 0.f};

    const int srow8 = lane >> 3;
    const int sls = ((lane & 7) ^ srow8) * 8;

    for (int k0 = 0; k0 < K; k0 += 64) {
        __syncthreads();
        #pragma unroll
        for (int j = 0; j < 6; ++j) {
            int c = 6 * w + j;                 // 0..23: 16 A-chunks, 8 B-chunks
            if (c < 16) {
                int row = c * 8 + srow8;
                gload_lds16(A + (size_t)(m0 + row) * K + k0 + sls, &As[c * 512]);
            } else {
                int row = (c - 16) * 8 + srow8;
                gload_lds16(B + (size_t)(n0 + row) * K + k0 + sls, &Bs[(c - 16) * 512]);
            }
        }
        __syncthreads();

        #pragma unroll
        for (int kc = 0; kc < 2; ++kc) {
            const int ph = ((kc * 4 + quad) ^ (l15 & 7)) * 8;
            bf16x8 av[2], bv[4];
            av[0] = ld_frag(&As[(w * 32 + l15) * 64 + ph]);
            av[1] = ld_frag(&As[(w * 32 + 16 + l15) * 64 + ph]);
            #pragma unroll
            for (int j = 0; j < 4; ++j)
                bv[j] = ld_frag(&Bs[(j * 16 + l15) * 64 + ph]);
            #pragma unroll
            for (int i = 0; i < 2; ++i)
                #pragma unroll
                for (int j = 0; j < 4; ++j)
                    acc[i][j] = MFMA(av[i], bv[j], acc[i][j]);
        }
    }

    #pragma unroll
    for (int i = 0; i < 2; ++i)
        #pragma unroll
        for (int j = 0; j < 4; ++j)
            #pragma unroll
            for (int r = 0; r < 4; ++r)
                C[(size_t)(m0 + w * 32 + i * 16 + quad * 4 + r) * N +
                  n0 + j * 16 + l15] = acc[i][j][r];
}

// ---------------------------------------------------------------------------
// Flash attention v7: fixed-reference softmax (post-RMSNorm scores bounded:
// |s| <= 11.4 -> exp sums ~2e8 << fp32 max) + K-tile 64 (half the barriers),
// async double-buffered staging. grid (32,16), 4 waves x 16 q-rows.
// LDS = 32K (Ks) + 32K (Vs) + 9K (Ps) = 73.75 KB -> 2 blocks/CU.
// ---------------------------------------------------------------------------
__global__ __launch_bounds__(256, 2) void attn_mfma(
    const bf16* __restrict__ qkvb, const bf16* __restrict__ vT,
    bf16* __restrict__ outb)
{
    __shared__ bf16 Ks[2][64 * 128];
    __shared__ bf16 Vs[2][128 * 64];
    __shared__ bf16 Ps[4][16 * 72];

    const int x = blockIdx.x;
    const int h = blockIdx.y, kvh = h >> 1;
    int a = (x & 1) ? (31 - (x >> 1)) : (x >> 1);
    const int qb = (h < 8) ? a : 31 - a;       // heavy/light pairing across CUs
    const int tid = threadIdx.x, w = tid >> 6, lane = tid & 63;
    const int l15 = lane & 15, quad = lane >> 4;
    const int qw0 = qb * 64 + w * 16;          // this wave's 16 q-rows

    bf16x8 qf[4];
    #pragma unroll
    for (int dk = 0; dk < 4; ++dk)
        qf[dk] = ld_frag(qkvb + (size_t)(qw0 + l15) * QKV_N +
                         h * HD + dk * 32 + quad * 8);

    f32x4 o[8];
    #pragma unroll
    for (int dt = 0; dt < 8; ++dt) o[dt] = f32x4{0.f, 0.f, 0.f, 0.f};
    float l_st = 0.f;                          // lane-partial sum of P

    // waves 0,1 stage K (64x128); waves 2,3 stage V^T (128x64)
    auto stage = [&](int t, int nb) {
        const int kt0 = t * 64;
        if (w < 2) {
            #pragma unroll
            for (int c = 0; c < 8; ++c) {
                int chunk = w * 8 + c;                 // 0..15
                int row = 4 * chunk + (lane >> 4);
                int ls = (lane & 15) ^ (row & 15);
                gload_lds16(qkvb + (size_t)(kt0 + row) * QKV_N + HID +
                            kvh * HD + ls * 8,
                            &Ks[nb][chunk * 512]);
            }
        } else {
            #pragma unroll
            for (int c = 0; c < 8; ++c) {
                int chunk = (w - 2) * 8 + c;           // 0..15
                int row = 8 * chunk + (lane >> 3);
                int ls = (lane & 7) ^ ((lane >> 3) & 7);
                gload_lds16(vT + (size_t)(kvh * HD + row) * S_LEN + kt0 + ls * 8,
                            &Vs[nb][chunk * 512]);
            }
        }
    };

    stage(0, 0);
    for (int t = 0; t <= qb; ++t) {
        const int pp = t & 1;
        const int kt0 = t * 64;
        __syncthreads();                  // drains stage(t)
        if (t < qb) stage(t + 1, pp ^ 1);

        // ---- S^T = K Q^T  (log2e pre-folded into q) ----
        f32x4 sc[4];
        #pragma unroll
        for (int mt = 0; mt < 4; ++mt) sc[mt] = f32x4{0.f, 0.f, 0.f, 0.f};
        #pragma unroll
        for (int dk = 0; dk < 4; ++dk)
            #pragma unroll
            for (int mt = 0; mt < 4; ++mt) {
                bf16x8 kf = ld_frag(&Ks[pp][(mt * 16 + l15) * 128 +
                                            (((dk * 4 + quad) ^ l15) & 15) * 8]);
                sc[mt] = MFMA(kf, qf[dk], sc[mt]);
            }

        // ---- causal mask (diagonal tile only: t == qb) ----
        if (kt0 + 63 > qw0) {
            #pragma unroll
            for (int mt = 0; mt < 4; ++mt)
                #pragma unroll
                for (int r = 0; r < 4; ++r) {
                    int kg = kt0 + mt * 16 + quad * 4 + r;
                    if (kg > qw0 + l15) sc[mt][r] = -1e30f;
                }
        }

        // ---- P = exp2(sc), lane-partial l, pack -> Ps ----
        #pragma unroll
        for (int mt = 0; mt < 4; ++mt) {
            union { uint2 u; bf16 hh[4]; } pk;
            #pragma unroll
            for (int r = 0; r < 4; ++r) {
                float p = exp2f(sc[mt][r]);
                pk.hh[r] = __float2bfloat16(p);
                l_st += p;
            }
            *(uint2*)&Ps[w][l15 * 72 + mt * 16 + quad * 4] = pk.u;
        }

        // ---- O^T += V^T P^T ----
        #pragma unroll
        for (int kc = 0; kc < 2; ++kc) {
            bf16x8 pf = ld_frag(&Ps[w][l15 * 72 + kc * 32 + quad * 8]);
            #pragma unroll
            for (int dt = 0; dt < 8; ++dt) {
                bf16x8 vf = ld_frag(&Vs[pp][(dt * 16 + l15) * 64 +
                                            (((kc * 4 + quad) ^ (l15 & 7)) * 8)]);
                o[dt] = MFMA(vf, pf, o[dt]);
            }
        }
    }

    // ---- epilogue: reduce l across quads once, divide, store ----
    l_st += __shfl_xor(l_st, 16, 64);
    l_st += __shfl_xor(l_st, 32, 64);
    float inv = 1.0f / l_st;
    int qg = qw0 + l15;
    #pragma unroll
    for (int dt = 0; dt < 8; ++dt) {
        union { uint2 u; bf16 hh[4]; } pk;
        #pragma unroll
        for (int r = 0; r < 4; ++r)
            pk.hh[r] = __float2bfloat16(o[dt][r] * inv);
        *(uint2*)&outb[(size_t)qg * HID + h * HD + dt * 16 + quad * 4] = pk.u;
    }
}

// ---------------------------------------------------------------------------
extern "C" void kernel_launch(void* const* d_in, const int* in_sizes, int n_in,
                              void* d_out, int out_size, void* d_ws, size_t ws_size,
                              hipStream_t stream) {
    const float* hidden = (const float*)d_in[0];
    const float* fcos   = (const float*)d_in[1];
    const float* fsin   = (const float*)d_in[2];
    // d_in[3] atten_mask: causal, applied analytically
    const float* Wq = (const float*)d_in[4];
    const float* Wk = (const float*)d_in[5];
    const float* Wv = (const float*)d_in[6];
    const float* Wo = (const float*)d_in[7];
    const float* qw = (const float*)d_in[8];
    const float* kw = (const float*)d_in[9];
    float* out = (float*)d_out;

    bf16* qkvb  = (bf16*)d_ws;                          // 2048 x 4096 (q|k normed)
    bf16* vT    = qkvb + (size_t)S_LEN * QKV_N;         // 1024 x 2048 (V^T)
    bf16* attnb = vT + (size_t)NKH * HD * S_LEN;        // 2048 x 2048
    bf16* wqkvb = attnb + (size_t)S_LEN * HID;          // 4096 x 2048
    bf16* hidb  = wqkvb + (size_t)QKV_N * HID;          // 2048 x 2048
    bf16* wob   = hidb + (size_t)S_LEN * HID;           // 2048 x 2048

    float* knew = out + (size_t)S_LEN * HID;
    float* vnew = knew + NKH * HD;

    // 0) all conversions in one launch (4M float4 units)
    cvt5<<<16384, 256, 0, stream>>>(
        hidden, Wq, Wk, Wv, Wo,
        hidb, wqkvb, wqkvb + (size_t)HID * HID,
        wqkvb + (size_t)(HID + NKH * HD) * HID, wob);

    // 1) QKV projection + fused RMSNorm/RoPE/QSCALE/V-transpose/knew/vnew
    //    128x128 tiles, BK=64 -> 512 blocks
    gemm_qkv<<<dim3(QKV_N / 128, S_LEN / 128), 256, 0, stream>>>(
        hidb, wqkvb, qkvb, vT, fcos, fsin, qw, kw, knew, vnew);

    // 2) causal GQA flash attention (bf16 out), fixed-ref softmax, K-tile 64
    attn_mfma<<<dim3(32, NH), 256, 0, stream>>>(qkvb, vT, attnb);

    // 3) output projection (fp32 out), 128x64 tiles BK=64 -> 512 blocks
    gemm_n64<<<dim3(HID / 64, S_LEN / 128), 256, 0, stream>>>(
        attnb, wob, out, S_LEN, HID, HID);
}

// Round 8
// 238.529 us; speedup vs baseline: 11.3502x; 1.0097x over previous
//
#include <hip/hip_runtime.h>
#include <hip/hip_bf16.h>
#include <math.h>

#define S_LEN 2048
#define HID 2048
#define NH 16
#define NKH 8
#define HD 128
#define QKV_N 4096
#define SCALE 0.08838834764831845f
#define EPS 1e-6f
#define LOG2E 1.4426950408889634f
#define QSCALE (SCALE * LOG2E)     // fold log2(e) into q so p = exp2(score)

typedef __hip_bfloat16 bf16;
typedef unsigned int u32;
typedef __bf16 bf16x8 __attribute__((ext_vector_type(8)));
typedef float f32x4 __attribute__((ext_vector_type(4)));

#define MFMA(a, b, c) __builtin_amdgcn_mfma_f32_16x16x32_bf16(a, b, c, 0, 0, 0)

static __device__ __forceinline__ bf16x8 ld_frag(const bf16* p) {
    return __builtin_bit_cast(bf16x8, *(const uint4*)p);
}

// async global->LDS, 16 B per lane. LDS dest = wave-uniform base + lane*16.
static __device__ __forceinline__ void gload_lds16(const void* g, void* l) {
    __builtin_amdgcn_global_load_lds(
        (const __attribute__((address_space(1))) u32*)g,
        (__attribute__((address_space(3))) u32*)l, 16, 0, 0);
}

// ---------------------------------------------------------------------------
// merged fp32 -> bf16: hidden | Wq | Wk | Wv | Wo in one launch.
// float4-unit thresholds: 1M | 2M | 2.5M | 3M | 4M. grid = 16384 x 256.
// ---------------------------------------------------------------------------
__global__ __launch_bounds__(256) void cvt5(
    const float* __restrict__ s0, const float* __restrict__ s1,
    const float* __restrict__ s2, const float* __restrict__ s3,
    const float* __restrict__ s4,
    bf16* __restrict__ d0, bf16* __restrict__ d1, bf16* __restrict__ d2,
    bf16* __restrict__ d3, bf16* __restrict__ d4)
{
    int i = blockIdx.x * 256 + threadIdx.x;
    const float* s; bf16* d; int off;
    if (i < (1 << 20))                   { s = s0; d = d0; off = 0; }
    else if (i < (2 << 20))              { s = s1; d = d1; off = 1 << 20; }
    else if (i < (2 << 20) + (1 << 19))  { s = s2; d = d2; off = 2 << 20; }
    else if (i < (3 << 20))              { s = s3; d = d3; off = (2 << 20) + (1 << 19); }
    else                                 { s = s4; d = d4; off = 3 << 20; }
    int j = i - off;
    float4 v = ((const float4*)s)[j];
    bf16* p = d + 4 * (size_t)j;
    p[0] = __float2bfloat16(v.x);
    p[1] = __float2bfloat16(v.y);
    p[2] = __float2bfloat16(v.z);
    p[3] = __float2bfloat16(v.w);
}

// ---------------------------------------------------------------------------
// QKV GEMM + fused epilogue. 128x128 tiles, BK=64, DOUBLE-BUFFERED
// global_load_lds staging (1 barrier/iter). Wave = 64x64 quadrant as 4x4
// MFMA grid -> 8 LDS reads per 16 MFMA. Column tiles interleaved
// (wcg + (j&1)*16 + (j>>1)*64) so the RoPE pair (d, d+64) = regs (j, j+2)
// of the SAME lane. RMSNorm sumsq crosses the 2 column-waves -> red[] LDS
// exchange + 1 barrier.
//   q heads: RMSNorm(qw)+RoPE, * SCALE*LOG2E -> qkvb
//   k heads: RMSNorm(kw)+RoPE -> qkvb; row 2047 -> knew (fp32)
//   v heads: raw -> vT transposed (packed uint2); row 2047 -> vnew
// ---------------------------------------------------------------------------
__global__ __launch_bounds__(256, 2) void gemm_qkv(
    const bf16* __restrict__ A, const bf16* __restrict__ B,
    bf16* __restrict__ qkvb, bf16* __restrict__ vT,
    const float* __restrict__ fcos, const float* __restrict__ fsin,
    const float* __restrict__ qw, const float* __restrict__ kw,
    float* __restrict__ knew, float* __restrict__ vnew)
{
    __shared__ bf16 As[2][128 * 64];
    __shared__ bf16 Bs[2][128 * 64];
    __shared__ float red[2][2][64];    // [row-half][col-wave][row]
    const int tid = threadIdx.x;
    const int n0 = blockIdx.x * 128, m0 = blockIdx.y * 128;
    const int w = tid >> 6, lane = tid & 63;
    const int l15 = lane & 15, quad = lane >> 4;
    const int wr = (w >> 1) * 64;      // wave row base
    const int wcg = (w & 1) * 32;      // wave column group base

    f32x4 acc[4][4];
    #pragma unroll
    for (int i = 0; i < 4; ++i)
        #pragma unroll
        for (int j = 0; j < 4; ++j)
            acc[i][j] = f32x4{0.f, 0.f, 0.f, 0.f};

    // staging: chunk = 8 rows x 64 k; lane -> row (lane>>3), phys slot lane&7
    const int srow8 = lane >> 3;
    const int sls = ((lane & 7) ^ srow8) * 8;   // logical k-slot fetched

    auto stage = [&](int k0, int nb) {
        #pragma unroll
        for (int j = 0; j < 8; ++j) {
            int c = 8 * w + j;                 // 0..31: 16 A-chunks, 16 B-chunks
            if (c < 16) {
                int row = c * 8 + srow8;
                gload_lds16(A + (size_t)(m0 + row) * HID + k0 + sls, &As[nb][c * 512]);
            } else {
                int row = (c - 16) * 8 + srow8;
                gload_lds16(B + (size_t)(n0 + row) * HID + k0 + sls, &Bs[nb][(c - 16) * 512]);
            }
        }
    };

    stage(0, 0);
    for (int kt = 0; kt < HID / 64; ++kt) {
        const int pp = kt & 1;
        __syncthreads();                       // drains stage(kt) -> buf pp ready
        if (kt + 1 < HID / 64) stage((kt + 1) * 64, pp ^ 1);

        #pragma unroll
        for (int kc = 0; kc < 2; ++kc) {
            const int ph = ((kc * 4 + quad) ^ (l15 & 7)) * 8;
            bf16x8 av[4], bv[4];
            #pragma unroll
            for (int i = 0; i < 4; ++i)
                av[i] = ld_frag(&As[pp][(wr + i * 16 + l15) * 64 + ph]);
            #pragma unroll
            for (int j = 0; j < 4; ++j)
                bv[j] = ld_frag(&Bs[pp][(wcg + (j & 1) * 16 + (j >> 1) * 64 + l15) * 64 + ph]);
            #pragma unroll
            for (int i = 0; i < 4; ++i)
                #pragma unroll
                for (int j = 0; j < 4; ++j)
                    acc[i][j] = MFMA(av[i], bv[j], acc[i][j]);
        }
    }

    const int hblk = n0 >> 7;          // 0..15 q | 16..23 k | 24..31 v
    if (hblk < 24) {
        // ---- cross-wave sumsq exchange ----
        float ssq[4][4];
        #pragma unroll
        for (int i = 0; i < 4; ++i)
            #pragma unroll
            for (int rr = 0; rr < 4; ++rr) {
                float ss = 0.f;
                #pragma unroll
                for (int j = 0; j < 4; ++j) ss += acc[i][j][rr] * acc[i][j][rr];
                ss += __shfl_xor(ss, 1);
                ss += __shfl_xor(ss, 2);
                ss += __shfl_xor(ss, 4);
                ss += __shfl_xor(ss, 8);
                ssq[i][rr] = ss;
                if (l15 == 0)
                    red[w >> 1][w & 1][i * 16 + quad * 4 + rr] = ss;
            }
        __syncthreads();

        const float* wgt = (hblk < 16) ? qw : kw;
        float wv[4];
        #pragma unroll
        for (int j = 0; j < 4; ++j)
            wv[j] = wgt[wcg + (j & 1) * 16 + (j >> 1) * 64 + l15];
        const size_t cb = (hblk < 16) ? (size_t)hblk * HD
                                      : (size_t)HID + (size_t)(hblk - 16) * HD;

        #pragma unroll
        for (int i = 0; i < 4; ++i)
            #pragma unroll
            for (int rr = 0; rr < 4; ++rr) {
                int rloc = i * 16 + quad * 4 + rr;
                int srow = m0 + wr + rloc;
                float tot = ssq[i][rr] + red[w >> 1][(w & 1) ^ 1][rloc];
                float rrn = rsqrtf(tot * (1.0f / 128.0f) + EPS);
                float x[4], res[4];
                #pragma unroll
                for (int j = 0; j < 4; ++j) x[j] = acc[i][j][rr] * rrn * wv[j];
                #pragma unroll
                for (int j2 = 0; j2 < 2; ++j2) {
                    float c = fcos[srow * 64 + wcg + j2 * 16 + l15];
                    float s = fsin[srow * 64 + wcg + j2 * 16 + l15];
                    res[j2]     = x[j2] * c - x[j2 + 2] * s;
                    res[j2 + 2] = x[j2] * s + x[j2 + 2] * c;
                }
                if (hblk < 16) {
                    #pragma unroll
                    for (int j = 0; j < 4; ++j)
                        qkvb[(size_t)srow * QKV_N + cb + wcg + (j & 1) * 16 +
                             (j >> 1) * 64 + l15] = __float2bfloat16(res[j] * QSCALE);
                } else {
                    #pragma unroll
                    for (int j = 0; j < 4; ++j)
                        qkvb[(size_t)srow * QKV_N + cb + wcg + (j & 1) * 16 +
                             (j >> 1) * 64 + l15] = __float2bfloat16(res[j]);
                    if (srow == S_LEN - 1) {
                        #pragma unroll
                        for (int j = 0; j < 4; ++j)
                            knew[(hblk - 16) * HD + wcg + (j & 1) * 16 +
                                 (j >> 1) * 64 + l15] = res[j];
                    }
                }
            }
    } else {
        const int kh = hblk - 24;
        #pragma unroll
        for (int i = 0; i < 4; ++i) {
            int rowbase = m0 + wr + i * 16 + quad * 4;
            #pragma unroll
            for (int j = 0; j < 4; ++j) {
                int d = wcg + (j & 1) * 16 + (j >> 1) * 64 + l15;
                union { uint2 u; bf16 hh[4]; } pk;
                #pragma unroll
                for (int r = 0; r < 4; ++r)
                    pk.hh[r] = __float2bfloat16(acc[i][j][r]);
                *(uint2*)&vT[(size_t)(kh * HD + d) * S_LEN + rowbase] = pk.u;
                if (rowbase == S_LEN - 4)
                    vnew[kh * HD + d] = acc[i][j][3];
            }
        }
    }
}

// ---------------------------------------------------------------------------
// 128(M)x64(N)-tile GEMM, BK=64, double-buffered, fp32 out — out-projection
// (512 blocks). LDS 48 KB.
// ---------------------------------------------------------------------------
__global__ __launch_bounds__(256, 2) void gemm_n64(
    const bf16* __restrict__ A, const bf16* __restrict__ B,
    float* __restrict__ C, int M, int N, int K)
{
    __shared__ bf16 As[2][128 * 64];
    __shared__ bf16 Bs[2][64 * 64];
    const int tid = threadIdx.x;
    const int n0 = blockIdx.x * 64, m0 = blockIdx.y * 128;
    const int w = tid >> 6, lane = tid & 63;
    const int l15 = lane & 15, quad = lane >> 4;

    f32x4 acc[2][4];
    #pragma unroll
    for (int i = 0; i < 2; ++i)
        #pragma unroll
        for (int j = 0; j < 4; ++j)
            acc[i][j] = f32x4{0.f, 0.f, 0.f, 0.f};

    const int srow8 = lane >> 3;
    const int sls = ((lane & 7) ^ srow8) * 8;

    auto stage = [&](int k0, int nb) {
        #pragma unroll
        for (int j = 0; j < 6; ++j) {
            int c = 6 * w + j;                 // 0..23: 16 A-chunks, 8 B-chunks
            if (c < 16) {
                int row = c * 8 + srow8;
                gload_lds16(A + (size_t)(m0 + row) * K + k0 + sls, &As[nb][c * 512]);
            } else {
                int row = (c - 16) * 8 + srow8;
                gload_lds16(B + (size_t)(n0 + row) * K + k0 + sls, &Bs[nb][(c - 16) * 512]);
            }
        }
    };

    stage(0, 0);
    for (int kt = 0; kt < K / 64; ++kt) {
        const int pp = kt & 1;
        __syncthreads();
        if (kt + 1 < K / 64) stage((kt + 1) * 64, pp ^ 1);

        #pragma unroll
        for (int kc = 0; kc < 2; ++kc) {
            const int ph = ((kc * 4 + quad) ^ (l15 & 7)) * 8;
            bf16x8 av[2], bv[4];
            av[0] = ld_frag(&As[pp][(w * 32 + l15) * 64 + ph]);
            av[1] = ld_frag(&As[pp][(w * 32 + 16 + l15) * 64 + ph]);
            #pragma unroll
            for (int j = 0; j < 4; ++j)
                bv[j] = ld_frag(&Bs[pp][(j * 16 + l15) * 64 + ph]);
            #pragma unroll
            for (int i = 0; i < 2; ++i)
                #pragma unroll
                for (int j = 0; j < 4; ++j)
                    acc[i][j] = MFMA(av[i], bv[j], acc[i][j]);
        }
    }

    #pragma unroll
    for (int i = 0; i < 2; ++i)
        #pragma unroll
        for (int j = 0; j < 4; ++j)
            #pragma unroll
            for (int r = 0; r < 4; ++r)
                C[(size_t)(m0 + w * 32 + i * 16 + quad * 4 + r) * N +
                  n0 + j * 16 + l15] = acc[i][j][r];
}

// ---------------------------------------------------------------------------
// Flash attention v7 (unchanged from R7): fixed-reference softmax, K-tile 64,
// async double-buffered staging. grid (32,16), 4 waves x 16 q-rows.
// ---------------------------------------------------------------------------
__global__ __launch_bounds__(256, 2) void attn_mfma(
    const bf16* __restrict__ qkvb, const bf16* __restrict__ vT,
    bf16* __restrict__ outb)
{
    __shared__ bf16 Ks[2][64 * 128];
    __shared__ bf16 Vs[2][128 * 64];
    __shared__ bf16 Ps[4][16 * 72];

    const int x = blockIdx.x;
    const int h = blockIdx.y, kvh = h >> 1;
    int a = (x & 1) ? (31 - (x >> 1)) : (x >> 1);
    const int qb = (h < 8) ? a : 31 - a;       // heavy/light pairing across CUs
    const int tid = threadIdx.x, w = tid >> 6, lane = tid & 63;
    const int l15 = lane & 15, quad = lane >> 4;
    const int qw0 = qb * 64 + w * 16;          // this wave's 16 q-rows

    bf16x8 qf[4];
    #pragma unroll
    for (int dk = 0; dk < 4; ++dk)
        qf[dk] = ld_frag(qkvb + (size_t)(qw0 + l15) * QKV_N +
                         h * HD + dk * 32 + quad * 8);

    f32x4 o[8];
    #pragma unroll
    for (int dt = 0; dt < 8; ++dt) o[dt] = f32x4{0.f, 0.f, 0.f, 0.f};
    float l_st = 0.f;                          // lane-partial sum of P

    // waves 0,1 stage K (64x128); waves 2,3 stage V^T (128x64)
    auto stage = [&](int t, int nb) {
        const int kt0 = t * 64;
        if (w < 2) {
            #pragma unroll
            for (int c = 0; c < 8; ++c) {
                int chunk = w * 8 + c;                 // 0..15
                int row = 4 * chunk + (lane >> 4);
                int ls = (lane & 15) ^ (row & 15);
                gload_lds16(qkvb + (size_t)(kt0 + row) * QKV_N + HID +
                            kvh * HD + ls * 8,
                            &Ks[nb][chunk * 512]);
            }
        } else {
            #pragma unroll
            for (int c = 0; c < 8; ++c) {
                int chunk = (w - 2) * 8 + c;           // 0..15
                int row = 8 * chunk + (lane >> 3);
                int ls = (lane & 7) ^ ((lane >> 3) & 7);
                gload_lds16(vT + (size_t)(kvh * HD + row) * S_LEN + kt0 + ls * 8,
                            &Vs[nb][chunk * 512]);
            }
        }
    };

    stage(0, 0);
    for (int t = 0; t <= qb; ++t) {
        const int pp = t & 1;
        const int kt0 = t * 64;
        __syncthreads();                  // drains stage(t)
        if (t < qb) stage(t + 1, pp ^ 1);

        // ---- S^T = K Q^T  (log2e pre-folded into q) ----
        f32x4 sc[4];
        #pragma unroll
        for (int mt = 0; mt < 4; ++mt) sc[mt] = f32x4{0.f, 0.f, 0.f, 0.f};
        #pragma unroll
        for (int dk = 0; dk < 4; ++dk)
            #pragma unroll
            for (int mt = 0; mt < 4; ++mt) {
                bf16x8 kf = ld_frag(&Ks[pp][(mt * 16 + l15) * 128 +
                                            (((dk * 4 + quad) ^ l15) & 15) * 8]);
                sc[mt] = MFMA(kf, qf[dk], sc[mt]);
            }

        // ---- causal mask (diagonal tile only: t == qb) ----
        if (kt0 + 63 > qw0) {
            #pragma unroll
            for (int mt = 0; mt < 4; ++mt)
                #pragma unroll
                for (int r = 0; r < 4; ++r) {
                    int kg = kt0 + mt * 16 + quad * 4 + r;
                    if (kg > qw0 + l15) sc[mt][r] = -1e30f;
                }
        }

        // ---- P = exp2(sc), lane-partial l, pack -> Ps ----
        #pragma unroll
        for (int mt = 0; mt < 4; ++mt) {
            union { uint2 u; bf16 hh[4]; } pk;
            #pragma unroll
            for (int r = 0; r < 4; ++r) {
                float p = exp2f(sc[mt][r]);
                pk.hh[r] = __float2bfloat16(p);
                l_st += p;
            }
            *(uint2*)&Ps[w][l15 * 72 + mt * 16 + quad * 4] = pk.u;
        }

        // ---- O^T += V^T P^T ----
        #pragma unroll
        for (int kc = 0; kc < 2; ++kc) {
            bf16x8 pf = ld_frag(&Ps[w][l15 * 72 + kc * 32 + quad * 8]);
            #pragma unroll
            for (int dt = 0; dt < 8; ++dt) {
                bf16x8 vf = ld_frag(&Vs[pp][(dt * 16 + l15) * 64 +
                                            (((kc * 4 + quad) ^ (l15 & 7)) * 8)]);
                o[dt] = MFMA(vf, pf, o[dt]);
            }
        }
    }

    // ---- epilogue: reduce l across quads once, divide, store ----
    l_st += __shfl_xor(l_st, 16, 64);
    l_st += __shfl_xor(l_st, 32, 64);
    float inv = 1.0f / l_st;
    int qg = qw0 + l15;
    #pragma unroll
    for (int dt = 0; dt < 8; ++dt) {
        union { uint2 u; bf16 hh[4]; } pk;
        #pragma unroll
        for (int r = 0; r < 4; ++r)
            pk.hh[r] = __float2bfloat16(o[dt][r] * inv);
        *(uint2*)&outb[(size_t)qg * HID + h * HD + dt * 16 + quad * 4] = pk.u;
    }
}

// ---------------------------------------------------------------------------
extern "C" void kernel_launch(void* const* d_in, const int* in_sizes, int n_in,
                              void* d_out, int out_size, void* d_ws, size_t ws_size,
                              hipStream_t stream) {
    const float* hidden = (const float*)d_in[0];
    const float* fcos   = (const float*)d_in[1];
    const float* fsin   = (const float*)d_in[2];
    // d_in[3] atten_mask: causal, applied analytically
    const float* Wq = (const float*)d_in[4];
    const float* Wk = (const float*)d_in[5];
    const float* Wv = (const float*)d_in[6];
    const float* Wo = (const float*)d_in[7];
    const float* qw = (const float*)d_in[8];
    const float* kw = (const float*)d_in[9];
    float* out = (float*)d_out;

    bf16* qkvb  = (bf16*)d_ws;                          // 2048 x 4096 (q|k normed)
    bf16* vT    = qkvb + (size_t)S_LEN * QKV_N;         // 1024 x 2048 (V^T)
    bf16* attnb = vT + (size_t)NKH * HD * S_LEN;        // 2048 x 2048
    bf16* wqkvb = attnb + (size_t)S_LEN * HID;          // 4096 x 2048
    bf16* hidb  = wqkvb + (size_t)QKV_N * HID;          // 2048 x 2048
    bf16* wob   = hidb + (size_t)S_LEN * HID;           // 2048 x 2048

    float* knew = out + (size_t)S_LEN * HID;
    float* vnew = knew + NKH * HD;

    // 0) all conversions in one launch (4M float4 units)
    cvt5<<<16384, 256, 0, stream>>>(
        hidden, Wq, Wk, Wv, Wo,
        hidb, wqkvb, wqkvb + (size_t)HID * HID,
        wqkvb + (size_t)(HID + NKH * HD) * HID, wob);

    // 1) QKV projection + fused RMSNorm/RoPE/QSCALE/V-transpose/knew/vnew
    //    128x128 tiles, BK=64, dbuf, quadrant waves -> 512 blocks
    gemm_qkv<<<dim3(QKV_N / 128, S_LEN / 128), 256, 0, stream>>>(
        hidb, wqkvb, qkvb, vT, fcos, fsin, qw, kw, knew, vnew);

    // 2) causal GQA flash attention (bf16 out), fixed-ref softmax, K-tile 64
    attn_mfma<<<dim3(32, NH), 256, 0, stream>>>(qkvb, vT, attnb);

    // 3) output projection (fp32 out), 128x64 tiles BK=64 dbuf -> 512 blocks
    gemm_n64<<<dim3(HID / 64, S_LEN / 128), 256, 0, stream>>>(
        attnb, wob, out, S_LEN, HID, HID);
}